// Round 8
// baseline (17721.431 us; speedup 1.0000x reference)
//
#include <hip/hip_runtime.h>
#include <cmath>

typedef _Float16 f16;
typedef _Float16 f16x8 __attribute__((ext_vector_type(8)));
typedef float f32x4 __attribute__((ext_vector_type(4)));
typedef unsigned long long u64;

#define MFMA_F16(a,b,c) __builtin_amdgcn_mfma_f32_16x16x32_f16((a),(b),(c),0,0,0)
#define AGENT __HIP_MEMORY_SCOPE_AGENT

// N=64, A=128, MO=126, LX=96, H=1024, S=32, P=2, B=16, BL=32, T=448
#define TSTEPS 448
#define OFF_MU 3612672   // 64*126*448
#define OFF_LV 4530176   // + 64*32*448
#define LDS_BYTES 156160

// signal classes (per-block flags: flag(cls, idx) = bar[(cls*64+idx)*32])
#define S1 0   // ineB ready        (64 signalers, idx b-64)
#define S2 1   // h0B ready         (64, idx b)
#define S3 2   // h1B ready         (64, idx b-64)
#define S3B 3  // gh0(t+1) ready    (64, idx b-128)
#define S4G 4  // gh1 + predsT      (64, idx b-192)

struct Ptrs {
  const float *aud, *mo, *lxm, *eps;
  const int *vid;
  const float *csi_w0, *csi_b0, *csi_w1, *csi_b1, *csi_w2, *csi_b2;
  const float *spk, *mu_w, *mu_b, *lv_w, *lv_b;
  const float *embW, *embB;
  const float *wih0, *whh0, *bih0, *bhh0;
  const float *wih1, *whh1, *bih1, *bhh1;
  const float *ln_g, *ln_b, *predW, *predB;
  float *out;
  unsigned *bar;
  float *mu5, *lv5, *h0F, *h1F, *gsbs, *g2b2;
  f16 *h0B, *h1B, *ineB, *xcat;
  float *ghP0, *ghP1, *x0, *x1, *predsT;
  f16 *whh0P, *whh1P, *wih0aP, *wih0bP, *wih1P, *embWP, *predWP, *wcP, *weP;
};

__device__ __forceinline__ float geluf(float x) {
  return 0.5f * x * (1.0f + erff(x * 0.7071067811865475f));
}
// fast sigmoid/tanh: __expf + v_rcp (abs err ~1e-6, tolerance is 1.5e-2)
__device__ __forceinline__ float sigmf(float x) {
  return __builtin_amdgcn_rcpf(1.0f + __expf(-x));
}
__device__ __forceinline__ float tanhf_fast(float x) {
  float xc = fmaxf(x, -44.f);           // avoid exp overflow -> -inf*0 NaN
  float e = __expf(-2.f * xc);
  return (1.f - e) * __builtin_amdgcn_rcpf(1.f + e);
}

// ---- coherent (cross-XCD) primitives: compiler-visible, batchable ----
__device__ __forceinline__ u64 ldc8(const void* p) {
  return __hip_atomic_load((const u64*)p, __ATOMIC_RELAXED, AGENT);
}
__device__ __forceinline__ void stc8(void* p, u64 v) {
  __hip_atomic_store((u64*)p, v, __ATOMIC_RELAXED, AGENT);
}
__device__ __forceinline__ void stcf(float* p, float v) {
  __hip_atomic_store(p, v, __ATOMIC_RELAXED, AGENT);
}
__device__ __forceinline__ f16x8 toH(u64 a, u64 b) {
  union { u64 u[2]; f16x8 h; } r; r.u[0] = a; r.u[1] = b; return r.h;
}
__device__ __forceinline__ f32x4 toF(u64 a, u64 b) {
  union { u64 u[2]; f32x4 f; } r; r.u[0] = a; r.u[1] = b; return r.f;
}
__device__ __forceinline__ u64 packF2(float a, float b) {
  union { float f[2]; u64 u; } r; r.f[0] = a; r.f[1] = b; return r.u;
}
// pack (v, lane^1's v) into 2 f16 and store 4B coherently from even lanes
__device__ __forceinline__ void st_pair(f16* base, float v, int lm, bool pred) {
  float vn = __shfl_xor(v, 1);
  if (!(lm & 1) && pred) {
    union { f16 h[2]; unsigned u; } pk;
    pk.h[0] = (f16)v; pk.h[1] = (f16)vn;
    __hip_atomic_store((unsigned*)base, pk.u, __ATOMIC_RELAXED, AGENT);
  }
}

// ---------------- prologue kernels ----------------

__global__ void k_init(Ptrs p) {
  int gid = blockIdx.x * 256 + threadIdx.x;
  if (gid < 16384) p.bar[gid] = 0u;
}

__global__ void k_pack(const float* __restrict__ src, f16* __restrict__ dst,
                       int K, int rowOff, int realN, int ldN,
                       const float* __restrict__ scale) {
  int ct = blockIdx.x, kt = blockIdx.y;
  int e = threadIdx.x * 2;
  int l = e >> 3, i = e & 7;
  int k = kt * 32 + (l >> 4) * 8 + i;
  int col = ct * 16 + (l & 15);
  f16 v0 = (f16)0.f, v1 = (f16)0.f;
  if (k < K && col < realN) {
    float s = scale ? scale[rowOff + k] : 1.f;
    v0 = (f16)(src[(size_t)(rowOff + k) * ldN + col] * s);
  }
  if (k + 1 < K && col < realN) {
    float s = scale ? scale[rowOff + k + 1] : 1.f;
    v1 = (f16)(src[(size_t)(rowOff + k + 1) * ldN + col] * s);
  }
  size_t o = ((size_t)ct * gridDim.y + kt) * 512 + e;
  dst[o] = v0; dst[o + 1] = v1;
}

// Gs[m] = sum_k ln_g[k]*predW[k,m]; Bs[m] = sum_k ln_b[k]*predW[k,m]
__global__ void k_gsbs(Ptrs p) {
  int c = threadIdx.x;
  if (c < 126) {
    float gs = 0.f, bs = 0.f;
    for (int k = 0; k < 1024; k++) {
      float w = p.predW[(size_t)k * 126 + c];
      gs += p.ln_g[k] * w;
      bs += p.ln_b[k] * w;
    }
    p.gsbs[c] = gs; p.gsbs[128 + c] = bs;
  }
}

// composed-through-pred vectors:
// G2[c3]=Gs@wih0_pred, B2[c3]=(Bs+predB)@wih0_pred (c3<3072);
// G2e[c]=Gs@embW_pred, B2e[c]=(Bs+predB)@embW_pred (c<1024)
__global__ void k_g2b2(Ptrs p) {
  int gid = blockIdx.x * 256 + threadIdx.x;
  if (gid < 3072) {
    float g2 = 0.f, b2 = 0.f;
    for (int m = 0; m < 126; m++) {
      float w = p.wih0[(size_t)(1024 + m) * 3072 + gid];
      g2 += p.gsbs[m] * w;
      b2 += (p.gsbs[128 + m] + p.predB[m]) * w;
    }
    p.g2b2[gid] = g2; p.g2b2[3072 + gid] = b2;
  } else if (gid < 4096) {
    int c = gid - 3072;
    float g2 = 0.f, b2 = 0.f;
    for (int m = 0; m < 126; m++) {
      float w = p.embW[(size_t)m * 1024 + c];
      g2 += p.gsbs[m] * w;
      b2 += (p.gsbs[128 + m] + p.predB[m]) * w;
    }
    p.g2b2[6144 + c] = g2; p.g2b2[7168 + c] = b2;
  }
}

// Wc = predWg(1024x126) @ wih0[1024:1150,:] packed in B-fragment order per BB block:
// wcP[((b*3+g)*32+kt)*512 + e]
__global__ void k_cwc(Ptrs p) {
  int gid = blockIdx.x * 256 + threadIdx.x;   // 3145728
  int e = gid & 511; int rest = gid >> 9;
  int kt = rest & 31; rest >>= 5;
  int g = rest % 3; int b = rest / 3;
  int l = e >> 3, i = e & 7;
  int k = kt * 32 + (l >> 4) * 8 + i;
  int col = b * 16 + (l & 15) + g * 1024;
  float acc = 0.f;
  const float* prow = p.predW + (size_t)k * 126;
  const float* wcol = p.wih0 + (size_t)1024 * 3072 + col;
  for (int m = 0; m < 126; m++) acc += prow[m] * wcol[(size_t)m * 3072];
  p.wcP[gid] = (f16)(acc * p.ln_g[k]);
}

// We = predWg @ embW[0:126,:] packed per CB block: weP[(cb*32+kt)*512 + e]
__global__ void k_cwe(Ptrs p) {
  int gid = blockIdx.x * 256 + threadIdx.x;   // 1048576
  int e = gid & 511; int rest = gid >> 9;
  int kt = rest & 31; int cb = rest >> 5;
  int l = e >> 3, i = e & 7;
  int k = kt * 32 + (l >> 4) * 8 + i;
  int col = cb * 16 + (l & 15);
  float acc = 0.f;
  const float* prow = p.predW + (size_t)k * 126;
  const float* wcol = p.embW + col;
  for (int m = 0; m < 126; m++) acc += prow[m] * wcol[(size_t)m * 1024];
  p.weP[gid] = (f16)(acc * p.ln_g[k]);
}

// zero xcat pred region for t>=1 (composed path never writes it; avoids NaN garbage)
__global__ void k_zpred(Ptrs p) {
  int gid = blockIdx.x * 256 + threadIdx.x;   // 447*64*63 = 1802304
  if (gid >= 1802304) return;
  int c2 = gid % 63; int u = gid / 63;
  int n = u & 63; int t = (u >> 6) + 1;
  ((unsigned*)p.xcat)[((size_t)(t * 64 + n)) * 192 + c2] = 0u;
}

__global__ void k_csi1(Ptrs p) {
  int gid = blockIdx.x * 256 + threadIdx.x;  // 65536
  int n = gid >> 10, c = gid & 1023;
  float acc = p.csi_b0[c];
  const float* w = p.csi_w0 + c;
  for (int k = 0; k < 126; k++) acc += p.mo[((size_t)(n * 126 + k)) * 512 + 31] * w[(size_t)k * 1024];
  for (int k = 0; k < 96; k++)  acc += p.lxm[(size_t)(n * 96 + k) * 16] * w[(size_t)(126 + k) * 1024];
  p.x0[gid] = geluf(acc);
}

__global__ void k_csi2(Ptrs p) {
  int gid = blockIdx.x * 256 + threadIdx.x;
  int n = gid >> 10, c = gid & 1023;
  float acc = p.csi_b1[c];
  const float* w = p.csi_w1 + c;
  const float* x = p.x0 + (size_t)n * 1024;
  for (int k = 0; k < 1024; k++) acc += x[k] * w[(size_t)k * 1024];
  p.x1[gid] = geluf(acc);
}

__global__ void k_csi3(Ptrs p) {
  int gid = blockIdx.x * 256 + threadIdx.x;
  int n = gid >> 11, c2 = gid & 2047;
  float acc = p.csi_b2[c2];
  const float* w = p.csi_w2 + c2;
  const float* x = p.x1 + (size_t)n * 1024;
  for (int k = 0; k < 1024; k++) acc += x[k] * w[(size_t)k * 2048];
  if (c2 < 1024) { p.h0F[n * 1024 + c2] = acc; p.h0B[n * 1024 + c2] = (f16)acc; }
  else           { p.h1F[n * 1024 + c2 - 1024] = acc; p.h1B[n * 1024 + c2 - 1024] = (f16)acc; }
}

// initial gh0/gh1 for t=0, packed per-consumer-lane records:
// ghP[((ct*16+lm)*16 + w*4+lq)*16 + g*4 + r], row = w*16+lq*4+r, col = g*1024 + ct*16+lm
__global__ void k_gh(Ptrs p) {
  int gid = blockIdx.x * 256 + threadIdx.x;  // 393216
  int which = gid >= 196608;
  int g2 = which ? gid - 196608 : gid;
  int n = g2 / 3072, c = g2 % 3072;
  const float* h = which ? p.h1F : p.h0F;
  const float* W = which ? p.whh1 : p.whh0;
  const float* bb = which ? p.bhh1 : p.bhh0;
  float acc = bb[c];
  const float* hr = h + (size_t)n * 1024;
  for (int k = 0; k < 1024; k++) acc += hr[k] * W[(size_t)k * 3072 + c];
  int g = c >> 10, col = c & 1023;
  int ct = col >> 4, lm = col & 15, w = n >> 4, lq = (n >> 2) & 3, r = n & 3;
  float* dst = which ? p.ghP1 : p.ghP0;
  dst[((size_t)((ct * 16 + lm) * 16 + w * 4 + lq)) * 16 + g * 4 + r] = acc;
}

__global__ void k_style1(Ptrs p) {
  int tid = threadIdx.x;
  if (tid < 160) {
    int v = tid >> 5, s = tid & 31;
    float m = p.mu_b[s], lv = p.lv_b[s];
    for (int k = 0; k < 32; k++) {
      float z = p.spk[v * 32 + k];
      m += z * p.mu_w[k * 32 + s];
      lv += z * p.lv_w[k * 32 + s];
    }
    p.mu5[v * 32 + s] = m; p.lv5[v * 32 + s] = lv;
  }
}

__global__ void k_style2(Ptrs p) {
  int gid = blockIdx.x * 256 + threadIdx.x;  // 917504
  int t = gid % 448;
  int rr = gid / 448;
  int s = rr & 31, n = rr >> 5;
  int v = p.vid[n * 16 + (t >> 5) + 1];
  float mu = p.mu5[v * 32 + s], lv = p.lv5[v * 32 + s];
  float e = p.eps[((size_t)t * 64 + n) * 32 + s];
  float st = mu + e * expf(0.5f * lv);
  p.out[OFF_MU + ((size_t)n * 32 + s) * 448 + t] = mu;
  p.out[OFF_LV + ((size_t)n * 32 + s) * 448 + t] = lv;
  p.xcat[((size_t)t * 64 + n) * 384 + 350 + s] = (f16)st;
}

__global__ void k_aud(Ptrs p) {
  __shared__ float tile[32][65];
  int bid = blockIdx.x;  // 64*4*7
  int n = bid / 28, rem = bid % 28;
  int a0 = (rem / 7) * 32, t0 = (rem % 7) * 64;
  int tid = threadIdx.x;
  for (int i = tid; i < 2048; i += 256) {
    int ai = i >> 6, tj = i & 63;
    tile[ai][tj] = p.aud[((size_t)n * 128 + a0 + ai) * 448 + t0 + tj];
  }
  __syncthreads();
  for (int i = tid; i < 2048; i += 256) {
    int tj = i >> 5, ai = i & 31;
    p.xcat[((size_t)(t0 + tj) * 64 + n) * 384 + 126 + a0 + ai] = (f16)tile[ai][tj];
  }
}

__global__ void k_lxm(Ptrs p) {
  int gid = blockIdx.x * 256 + threadIdx.x;  // 2752512
  int l_ = gid % 96;
  int r = gid / 96;
  int n = r & 63, t = r >> 6;
  int tb = (t >> 5) + 1;
  p.xcat[((size_t)t * 64 + n) * 384 + 254 + l_] = (f16)p.lxm[((size_t)n * 96 + l_) * 16 + tb];
}

__global__ void k_premo0(Ptrs p) {
  int gid = blockIdx.x * 256 + threadIdx.x;
  if (gid < 8064) {
    int n = gid / 126, m = gid % 126;
    p.xcat[(size_t)n * 384 + m] = (f16)p.mo[((size_t)n * 126 + m) * 512 + 31];
  }
}

__global__ void k_padz(Ptrs p) {
  int gid = blockIdx.x * 256 + threadIdx.x;  // 57344
  int t = gid >> 7, rem = gid & 127;
  int n = rem >> 1, c = 382 + (rem & 1);
  p.xcat[((size_t)t * 64 + n) * 384 + c] = (f16)0.f;
}

// ---------------- persistent scan kernel ----------------

// signal: drain stores, then plain agent store of step value (one writer/flag)
__device__ __forceinline__ void sigc(unsigned* bar, int cls, int idx, unsigned val) {
  asm volatile("s_waitcnt vmcnt(0)" ::: "memory");
  __syncthreads();
  if (threadIdx.x == 0)
    __hip_atomic_store(&bar[(cls * 64 + idx) * 32], val, __ATOMIC_RELAXED, AGENT);
}
// busy-poll: nsig lanes each watch one producer's flag
__device__ __forceinline__ void waitc(unsigned* bar, int cls, unsigned tgt, int nsig) {
  if (threadIdx.x < (unsigned)nsig) {
    const unsigned* f = &bar[(cls * 64 + threadIdx.x) * 32];
    while (__hip_atomic_load(f, __ATOMIC_RELAXED, AGENT) < tgt) {}
  }
  __syncthreads();
}

// pipelined 3-gate GEMM: A row coherent (batched u64 loads, double-buffered),
// weights LDS-resident at L+{0,16384,32768} (f16 offsets)
__device__ __forceinline__ void gemm3(const f16* aRow, const f16* L, int l,
                                      f32x4& A0, f32x4& A1, f32x4& A2) {
  const f16* w0 = L + l * 8;
  u64 ua[16], ub[16];
  #pragma unroll
  for (int j = 0; j < 8; j++) { ua[2*j] = ldc8(aRow + j * 32); ua[2*j+1] = ldc8(aRow + j * 32 + 4); }
  #pragma unroll
  for (int j = 0; j < 8; j++) { ub[2*j] = ldc8(aRow + 256 + j * 32); ub[2*j+1] = ldc8(aRow + 256 + j * 32 + 4); }
  #pragma unroll
  for (int j = 0; j < 8; j++) {
    f16x8 av = toH(ua[2*j], ua[2*j+1]);
    A0 = MFMA_F16(av, *(const f16x8*)(w0 + j * 512), A0);
    A1 = MFMA_F16(av, *(const f16x8*)(w0 + 16384 + j * 512), A1);
    A2 = MFMA_F16(av, *(const f16x8*)(w0 + 32768 + j * 512), A2);
  }
  #pragma unroll
  for (int j = 0; j < 8; j++) { ua[2*j] = ldc8(aRow + 512 + j * 32); ua[2*j+1] = ldc8(aRow + 512 + j * 32 + 4); }
  #pragma unroll
  for (int j = 0; j < 8; j++) {
    f16x8 av = toH(ub[2*j], ub[2*j+1]);
    int kt = 8 + j;
    A0 = MFMA_F16(av, *(const f16x8*)(w0 + kt * 512), A0);
    A1 = MFMA_F16(av, *(const f16x8*)(w0 + 16384 + kt * 512), A1);
    A2 = MFMA_F16(av, *(const f16x8*)(w0 + 32768 + kt * 512), A2);
  }
  #pragma unroll
  for (int j = 0; j < 8; j++) { ub[2*j] = ldc8(aRow + 768 + j * 32); ub[2*j+1] = ldc8(aRow + 768 + j * 32 + 4); }
  #pragma unroll
  for (int j = 0; j < 8; j++) {
    f16x8 av = toH(ua[2*j], ua[2*j+1]);
    int kt = 16 + j;
    A0 = MFMA_F16(av, *(const f16x8*)(w0 + kt * 512), A0);
    A1 = MFMA_F16(av, *(const f16x8*)(w0 + 16384 + kt * 512), A1);
    A2 = MFMA_F16(av, *(const f16x8*)(w0 + 32768 + kt * 512), A2);
  }
  #pragma unroll
  for (int j = 0; j < 8; j++) {
    f16x8 av = toH(ub[2*j], ub[2*j+1]);
    int kt = 24 + j;
    A0 = MFMA_F16(av, *(const f16x8*)(w0 + kt * 512), A0);
    A1 = MFMA_F16(av, *(const f16x8*)(w0 + 16384 + kt * 512), A1);
    A2 = MFMA_F16(av, *(const f16x8*)(w0 + 32768 + kt * 512), A2);
  }
}

// like gemm3 but additionally accumulates a 4th (pred) gate with B from LDS
// at L+49152 and in-GEMM LN stats (sum/sumsq of A elements)
__device__ __forceinline__ void gemm4s(const f16* aRow, const f16* L, int l,
                                       f32x4& A0, f32x4& A1, f32x4& A2,
                                       f32x4& P, float& ssum, float& ssq) {
  const f16* w0 = L + l * 8;
  u64 ua[16], ub[16];
  #pragma unroll
  for (int j = 0; j < 8; j++) { ua[2*j] = ldc8(aRow + j * 32); ua[2*j+1] = ldc8(aRow + j * 32 + 4); }
  #pragma unroll
  for (int j = 0; j < 8; j++) { ub[2*j] = ldc8(aRow + 256 + j * 32); ub[2*j+1] = ldc8(aRow + 256 + j * 32 + 4); }
  auto rnd = [&](u64* cur, int base) {
    #pragma unroll
    for (int j = 0; j < 8; j++) {
      int kt = base + j;
      f16x8 av = toH(cur[2*j], cur[2*j+1]);
      A0 = MFMA_F16(av, *(const f16x8*)(w0 + kt * 512), A0);
      A1 = MFMA_F16(av, *(const f16x8*)(w0 + 16384 + kt * 512), A1);
      A2 = MFMA_F16(av, *(const f16x8*)(w0 + 32768 + kt * 512), A2);
      P  = MFMA_F16(av, *(const f16x8*)(w0 + 49152 + kt * 512), P);
      #pragma unroll
      for (int e = 0; e < 8; e++) { float v = (float)av[e]; ssum += v; ssq += v * v; }
    }
  };
  rnd(ua, 0);
  #pragma unroll
  for (int j = 0; j < 8; j++) { ua[2*j] = ldc8(aRow + 512 + j * 32); ua[2*j+1] = ldc8(aRow + 512 + j * 32 + 4); }
  rnd(ub, 8);
  #pragma unroll
  for (int j = 0; j < 8; j++) { ub[2*j] = ldc8(aRow + 768 + j * 32); ub[2*j+1] = ldc8(aRow + 768 + j * 32 + 4); }
  rnd(ua, 16);
  rnd(ub, 24);
}

// composed 3-gate GEMM for BB: A = h1B row (coherent), B = wcP (global, cached,
// read-only), + in-GEMM LN stats
__device__ __forceinline__ void gemmW(const f16* aRow, const f16* wc, int l,
                                      f32x4& Q0, f32x4& Q1, f32x4& Q2,
                                      float& ssum, float& ssq) {
  const f16* w0 = wc + l * 8;
  u64 ua[16], ub[16];
  #pragma unroll
  for (int j = 0; j < 8; j++) { ua[2*j] = ldc8(aRow + j * 32); ua[2*j+1] = ldc8(aRow + j * 32 + 4); }
  #pragma unroll
  for (int j = 0; j < 8; j++) { ub[2*j] = ldc8(aRow + 256 + j * 32); ub[2*j+1] = ldc8(aRow + 256 + j * 32 + 4); }
  auto rnd = [&](u64* cur, int base) {
    #pragma unroll
    for (int j = 0; j < 8; j++) {
      int kt = base + j;
      f16x8 av = toH(cur[2*j], cur[2*j+1]);
      Q0 = MFMA_F16(av, *(const f16x8*)(w0 + kt * 512), Q0);
      Q1 = MFMA_F16(av, *(const f16x8*)(w0 + (32 + kt) * 512), Q1);
      Q2 = MFMA_F16(av, *(const f16x8*)(w0 + (64 + kt) * 512), Q2);
      #pragma unroll
      for (int e = 0; e < 8; e++) { float v = (float)av[e]; ssum += v; ssq += v * v; }
    }
  };
  rnd(ua, 0);
  #pragma unroll
  for (int j = 0; j < 8; j++) { ua[2*j] = ldc8(aRow + 512 + j * 32); ua[2*j+1] = ldc8(aRow + 512 + j * 32 + 4); }
  rnd(ub, 8);
  #pragma unroll
  for (int j = 0; j < 8; j++) { ub[2*j] = ldc8(aRow + 768 + j * 32); ub[2*j+1] = ldc8(aRow + 768 + j * 32 + 4); }
  rnd(ua, 16);
  rnd(ub, 24);
}

// composed 1-gate GEMM for CB: A = h1B row (coherent), B = We in LDS at L+55296,
// + in-GEMM LN stats
__device__ __forceinline__ void gemmE(const f16* aRow, const f16* L, int l,
                                      f32x4& Q, float& ssum, float& ssq) {
  const f16* w0 = L + 55296 + l * 8;
  u64 ua[16], ub[16];
  #pragma unroll
  for (int j = 0; j < 8; j++) { ua[2*j] = ldc8(aRow + j * 32); ua[2*j+1] = ldc8(aRow + j * 32 + 4); }
  #pragma unroll
  for (int j = 0; j < 8; j++) { ub[2*j] = ldc8(aRow + 256 + j * 32); ub[2*j+1] = ldc8(aRow + 256 + j * 32 + 4); }
  auto rnd = [&](u64* cur, int base) {
    #pragma unroll
    for (int j = 0; j < 8; j++) {
      int kt = base + j;
      f16x8 av = toH(cur[2*j], cur[2*j+1]);
      Q = MFMA_F16(av, *(const f16x8*)(w0 + kt * 512), Q);
      #pragma unroll
      for (int e = 0; e < 8; e++) { float v = (float)av[e]; ssum += v; ssq += v * v; }
    }
  };
  rnd(ua, 0);
  #pragma unroll
  for (int j = 0; j < 8; j++) { ua[2*j] = ldc8(aRow + 512 + j * 32); ua[2*j+1] = ldc8(aRow + 512 + j * 32 + 4); }
  rnd(ub, 8);
  #pragma unroll
  for (int j = 0; j < 8; j++) { ub[2*j] = ldc8(aRow + 768 + j * 32); ub[2*j+1] = ldc8(aRow + 768 + j * 32 + 4); }
  rnd(ua, 16);
  rnd(ub, 24);
}

__global__ __launch_bounds__(256, 1) void k_scan(Ptrs p) {
  extern __shared__ char smem[];
  f16* L = (f16*)smem;
  const int b = blockIdx.x, tid = threadIdx.x;
  const int w = tid >> 6, l = tid & 63;
  const int lm = l & 15, lq = l >> 4;

  // ---- one-time: stage weights into LDS (resident), preload biases ----
  {
    auto cp = [&](int dstF16, const f16* src, int nF16) {
      uint4* d = (uint4*)smem + (dstF16 >> 3);
      const uint4* s = (const uint4*)src;
      for (int i = tid; i < (nF16 >> 3); i += 256) d[i] = s[i];
    };
    if (b < 64) {
      cp(0,     p.wih0aP + (size_t)b * 16384, 16384);
      cp(16384, p.wih0aP + (size_t)(64 + b) * 16384, 16384);
      cp(32768, p.wih0aP + (size_t)(128 + b) * 16384, 16384);
      cp(49152, p.wih0bP + (size_t)b * 6144, 6144);
      cp(55296, p.wih0bP + (size_t)(64 + b) * 6144, 6144);
      cp(61440, p.wih0bP + (size_t)(128 + b) * 6144, 6144);
    } else if (b < 128) {
      int cb = b - 64;
      cp(0,     p.wih1P + (size_t)cb * 16384, 16384);
      cp(16384, p.wih1P + (size_t)(64 + cb) * 16384, 16384);
      cp(32768, p.wih1P + (size_t)(128 + cb) * 16384, 16384);
      cp(49152, p.embWP + (size_t)cb * 6144, 6144);
      cp(55296, p.weP + (size_t)cb * 16384, 16384);       // composed We slice
    } else if (b < 192) {
      int i = b - 128;
      cp(0,     p.whh0P + (size_t)i * 16384, 16384);
      cp(16384, p.whh0P + (size_t)(64 + i) * 16384, 16384);
      cp(32768, p.whh0P + (size_t)(128 + i) * 16384, 16384);
    } else {
      int i = b - 192;
      cp(0,     p.whh1P + (size_t)i * 16384, 16384);
      cp(16384, p.whh1P + (size_t)(64 + i) * 16384, 16384);
      cp(32768, p.whh1P + (size_t)(128 + i) * 16384, 16384);
      if (i < 8) cp(49152, p.predWP + (size_t)i * 16384, 16384);  // predWg slice
    }
  }
  // per-lane constant biases + persistent GRU state (h0 or h1 slice in regs)
  float b0r = 0.f, b1r = 0.f, b2r = 0.f, ebr = 0.f, pbr = 0.f;
  float GsR = 0.f, BsR = 0.f;
  float G2_0 = 0.f, G2_1 = 0.f, G2_2 = 0.f, B2_0 = 0.f, B2_1 = 0.f, B2_2 = 0.f;
  float hs[4] = {0.f, 0.f, 0.f, 0.f};
  if (b < 64) {
    int col = b * 16 + lm;
    b0r = p.bih0[col]; b1r = p.bih0[1024 + col]; b2r = p.bih0[2048 + col];
    G2_0 = p.g2b2[col];        B2_0 = p.g2b2[3072 + col];
    G2_1 = p.g2b2[1024 + col]; B2_1 = p.g2b2[3072 + 1024 + col];
    G2_2 = p.g2b2[2048 + col]; B2_2 = p.g2b2[3072 + 2048 + col];
    #pragma unroll
    for (int r = 0; r < 4; r++) hs[r] = p.h0F[(size_t)(w * 16 + lq * 4 + r) * 1024 + col];
  } else if (b < 128) {
    int col = (b - 64) * 16 + lm;
    b0r = p.bih1[col]; b1r = p.bih1[1024 + col]; b2r = p.bih1[2048 + col];
    ebr = p.embB[col];
    G2_0 = p.g2b2[6144 + col]; B2_0 = p.g2b2[7168 + col];
    #pragma unroll
    for (int r = 0; r < 4; r++) hs[r] = p.h1F[(size_t)(w * 16 + lq * 4 + r) * 1024 + col];
  } else if (b < 192) {
    int col = (b - 128) * 16 + lm;
    b0r = p.bhh0[col]; b1r = p.bhh0[1024 + col]; b2r = p.bhh0[2048 + col];
  } else {
    int col = (b - 192) * 16 + lm;
    b0r = p.bhh1[col]; b1r = p.bhh1[1024 + col]; b2r = p.bhh1[2048 + col];
    if (b < 200) {   // predsT-writer blocks: per-lane col constants
      int pc = (b - 192) * 16 + lm;
      if (pc < 126) { pbr = p.predB[pc]; GsR = p.gsbs[pc]; BsR = p.gsbs[128 + pc]; }
    }
  }
  __syncthreads();

  unsigned* bar = p.bar;

  for (unsigned t = 0; t < TSTEPS; t++) {
    const f16* xc = p.xcat + (size_t)t * 24576;

    if (b < 64) {
      // ============ BB: gip = static + composed(h1(t-1)) then h0n ============
      f32x4 a0 = {0,0,0,0}, a1 = {0,0,0,0}, a2 = {0,0,0,0};
      const f16* aB = xc + (w * 16 + lm) * 384 + lq * 8;
      const f16* wl = L + 49152 + l * 8;
      #pragma unroll
      for (int kt = 4; kt < 12; kt++) {
        f16x8 av = *(const f16x8*)(aB + kt * 32);
        a0 = MFMA_F16(av, *(const f16x8*)(wl + kt * 512), a0);
        a1 = MFMA_F16(av, *(const f16x8*)(wl + 6144 + kt * 512), a1);
        a2 = MFMA_F16(av, *(const f16x8*)(wl + 12288 + kt * 512), a2);
      }
      f32x4 q0 = {0,0,0,0}, q1 = {0,0,0,0}, q2 = {0,0,0,0};
      float mean_[4], rstd_[4];
      if (t) {
        // tile 3: pred rows zeroed in xcat (k_zpred); aud cols 126/127 live
        f16x8 av3 = *(const f16x8*)(aB + 3 * 32);
        a0 = MFMA_F16(av3, *(const f16x8*)(wl + 3 * 512), a0);
        a1 = MFMA_F16(av3, *(const f16x8*)(wl + 6144 + 3 * 512), a1);
        a2 = MFMA_F16(av3, *(const f16x8*)(wl + 12288 + 3 * 512), a2);
        waitc(bar, S3, t, 64);    // h1B(t-1) ready
        float ssum = 0.f, ssq = 0.f;
        gemmW(p.h1B + (w * 16 + lm) * 1024 + lq * 8, p.wcP + (size_t)b * 49152,
              l, q0, q1, q2, ssum, ssq);
        ssum += __shfl_xor(ssum, 16); ssq += __shfl_xor(ssq, 16);
        ssum += __shfl_xor(ssum, 32); ssq += __shfl_xor(ssq, 32);
        #pragma unroll
        for (int r = 0; r < 4; r++) {
          int src = (l & 48) | (lq * 4 + r);
          float ms = __shfl(ssum, src), qs = __shfl(ssq, src);
          float mean = ms * 0.0009765625f;
          float var  = qs * 0.0009765625f - mean * mean;
          mean_[r] = mean; rstd_[r] = rsqrtf(var + 1e-5f);
        }
      } else {
        u64 up[8];
        #pragma unroll
        for (int kt = 0; kt < 4; kt++) { up[2*kt] = ldc8(aB + kt * 32); up[2*kt+1] = ldc8(aB + kt * 32 + 4); }
        #pragma unroll
        for (int kt = 0; kt < 4; kt++) {
          f16x8 av = toH(up[2*kt], up[2*kt+1]);
          a0 = MFMA_F16(av, *(const f16x8*)(wl + kt * 512), a0);
          a1 = MFMA_F16(av, *(const f16x8*)(wl + 6144 + kt * 512), a1);
          a2 = MFMA_F16(av, *(const f16x8*)(wl + 12288 + kt * 512), a2);
        }
      }
      f32x4 gip0, gip1, gip2;
      #pragma unroll
      for (int r = 0; r < 4; r++) {
        if (t) {
          float rs = rstd_[r], rm = rstd_[r] * mean_[r];
          gip0[r] = a0[r] + b0r + rs * q0[r] - rm * G2_0 + B2_0;
          gip1[r] = a1[r] + b1r + rs * q1[r] - rm * G2_1 + B2_1;
          gip2[r] = a2[r] + b2r + rs * q2[r] - rm * G2_2 + B2_2;
        } else {
          gip0[r] = a0[r] + b0r; gip1[r] = a1[r] + b1r; gip2[r] = a2[r] + b2r;
        }
      }
      // gh0(t) produced off-path by GH0 last step: confirm flag, issue record loads
      waitc(bar, S3B, t, 64);
      const float* rec = p.ghP0 + ((size_t)((b * 16 + lm) * 16 + w * 4 + lq)) * 16;
      u64 r0 = ldc8(rec), r1 = ldc8(rec + 2), r2 = ldc8(rec + 4);
      u64 r3 = ldc8(rec + 6), r4 = ldc8(rec + 8), r5 = ldc8(rec + 10);
      waitc(bar, S1, t + 1, 64);
      {
        f32x4 A0 = {0,0,0,0}, A1 = {0,0,0,0}, A2 = {0,0,0,0};
        gemm3(p.ineB + (w * 16 + lm) * 1024 + lq * 8, L, l, A0, A1, A2);
        f32x4 g0 = toF(r0, r1), g1 = toF(r2, r3), g2 = toF(r4, r5);
        int col = b * 16 + lm;
        #pragma unroll
        for (int r = 0; r < 4; r++) {
          int row = w * 16 + lq * 4 + r;
          float r_ = sigmf(A0[r] + gip0[r] + g0[r]);
          float z_ = sigmf(A1[r] + gip1[r] + g1[r]);
          float n_ = tanhf_fast(A2[r] + gip2[r] + r_ * g2[r]);
          float hn = (1.f - z_) * n_ + z_ * hs[r];
          hs[r] = hn;
          st_pair(p.h0B + (size_t)row * 1024 + col, hn, lm, true);
        }
      }
      sigc(bar, S2, b, t + 1);
    } else if (b < 128) {
      // ============ CB: ine = static + composed(h1(t-1)); then h1n ============
      int cb = b - 64;
      int col = cb * 16 + lm;
      f32x4 acc = {0,0,0,0};
      const f16* aB = xc + (w * 16 + lm) * 384 + lq * 8;
      const f16* wl = L + 49152 + l * 8;
      #pragma unroll
      for (int kt = 4; kt < 12; kt++)
        acc = MFMA_F16(*(const f16x8*)(aB + kt * 32), *(const f16x8*)(wl + kt * 512), acc);
      f32x4 qe = {0,0,0,0};
      float mean_[4], rstd_[4];
      if (t) {
        f16x8 av3 = *(const f16x8*)(aB + 3 * 32);
        acc = MFMA_F16(av3, *(const f16x8*)(wl + 3 * 512), acc);
        waitc(bar, S3, t, 64);
        float ssum = 0.f, ssq = 0.f;
        gemmE(p.h1B + (w * 16 + lm) * 1024 + lq * 8, L, l, qe, ssum, ssq);
        ssum += __shfl_xor(ssum, 16); ssq += __shfl_xor(ssq, 16);
        ssum += __shfl_xor(ssum, 32); ssq += __shfl_xor(ssq, 32);
        #pragma unroll
        for (int r = 0; r < 4; r++) {
          int src = (l & 48) | (lq * 4 + r);
          float ms = __shfl(ssum, src), qs = __shfl(ssq, src);
          float mean = ms * 0.0009765625f;
          float var  = qs * 0.0009765625f - mean * mean;
          mean_[r] = mean; rstd_[r] = rsqrtf(var + 1e-5f);
        }
      } else {
        u64 up[8];
        #pragma unroll
        for (int kt = 0; kt < 4; kt++) { up[2*kt] = ldc8(aB + kt * 32); up[2*kt+1] = ldc8(aB + kt * 32 + 4); }
        #pragma unroll
        for (int kt = 0; kt < 4; kt++)
          acc = MFMA_F16(toH(up[2*kt], up[2*kt+1]), *(const f16x8*)(wl + kt * 512), acc);
      }
      #pragma unroll
      for (int r = 0; r < 4; r++) {
        int row = w * 16 + lq * 4 + r;
        float pre = acc[r] + ebr;
        if (t) pre += rstd_[r] * qe[r] - rstd_[r] * mean_[r] * G2_0 + B2_0;
        float v = geluf(pre);
        st_pair(p.ineB + (size_t)row * 1024 + col, v, lm, true);
      }
      sigc(bar, S1, cb, t + 1);
      // gh1(t) off-path: confirm flag, issue record loads, then wait h0 (S2)
      waitc(bar, S4G, t, 64);
      const float* rec = p.ghP1 + ((size_t)((cb * 16 + lm) * 16 + w * 4 + lq)) * 16;
      u64 r0 = ldc8(rec), r1 = ldc8(rec + 2), r2 = ldc8(rec + 4);
      u64 r3 = ldc8(rec + 6), r4 = ldc8(rec + 8), r5 = ldc8(rec + 10);
      waitc(bar, S2, t + 1, 64);
      {
        f32x4 A0 = {0,0,0,0}, A1 = {0,0,0,0}, A2 = {0,0,0,0};
        gemm3(p.h0B + (w * 16 + lm) * 1024 + lq * 8, L, l, A0, A1, A2);
        f32x4 g0 = toF(r0, r1), g1 = toF(r2, r3), g2 = toF(r4, r5);
        #pragma unroll
        for (int r = 0; r < 4; r++) {
          int row = w * 16 + lq * 4 + r;
          float r_ = sigmf(A0[r] + b0r + g0[r]);
          float z_ = sigmf(A1[r] + b1r + g1[r]);
          float n_ = tanhf_fast(A2[r] + b2r + r_ * g2[r]);
          float hn = (1.f - z_) * n_ + z_ * hs[r];
          hs[r] = hn;
          st_pair(p.h1B + (size_t)row * 1024 + col, hn, lm, true);
        }
      }
      sigc(bar, S3, cb, t + 1);
    } else if (b < 192) {
      // ================= GH0: gh0(t+1) =================
      int i = b - 128;
      waitc(bar, S2, t + 1, 64);
      {
        f32x4 A0 = {0,0,0,0}, A1 = {0,0,0,0}, A2 = {0,0,0,0};
        gemm3(p.h0B + (w * 16 + lm) * 1024 + lq * 8, L, l, A0, A1, A2);
        float* rec = p.ghP0 + ((size_t)((i * 16 + lm) * 16 + w * 4 + lq)) * 16;
        stc8(rec,      packF2(A0[0] + b0r, A0[1] + b0r));
        stc8(rec + 2,  packF2(A0[2] + b0r, A0[3] + b0r));
        stc8(rec + 4,  packF2(A1[0] + b1r, A1[1] + b1r));
        stc8(rec + 6,  packF2(A1[2] + b1r, A1[3] + b1r));
        stc8(rec + 8,  packF2(A2[0] + b2r, A2[1] + b2r));
        stc8(rec + 10, packF2(A2[2] + b2r, A2[3] + b2r));
      }
      sigc(bar, S3B, i, t + 1);
    } else {
      // ============ GH1: gh1(t+1); i<8 also pred(t) output (off-path) ============
      int i = b - 192;
      waitc(bar, S3, t + 1, 64);
      f32x4 A0 = {0,0,0,0}, A1 = {0,0,0,0}, A2 = {0,0,0,0};
      f32x4 P = {0,0,0,0};
      float ssum = 0.f, ssq = 0.f;
      if (i < 8)
        gemm4s(p.h1B + (w * 16 + lm) * 1024 + lq * 8, L, l, A0, A1, A2, P, ssum, ssq);
      else
        gemm3(p.h1B + (w * 16 + lm) * 1024 + lq * 8, L, l, A0, A1, A2);
      {
        float* rec = p.ghP1 + ((size_t)((i * 16 + lm) * 16 + w * 4 + lq)) * 16;
        stc8(rec,      packF2(A0[0] + b0r, A0[1] + b0r));
        stc8(rec + 2,  packF2(A0[2] + b0r, A0[3] + b0r));
        stc8(rec + 4,  packF2(A1[0] + b1r, A1[1] + b1r));
        stc8(rec + 6,  packF2(A1[2] + b1r, A1[3] + b1r));
        stc8(rec + 8,  packF2(A2[0] + b2r, A2[1] + b2r));
        stc8(rec + 10, packF2(A2[2] + b2r, A2[3] + b2r));
      }
      if (i < 8) {
        ssum += __shfl_xor(ssum, 16); ssq += __shfl_xor(ssq, 16);
        ssum += __shfl_xor(ssum, 32); ssq += __shfl_xor(ssq, 32);
        int pc = i * 16 + lm;
        #pragma unroll
        for (int r = 0; r < 4; r++) {
          int src = (l & 48) | (lq * 4 + r);
          float ms = __shfl(ssum, src), qs = __shfl(ssq, src);
          float mean = ms * 0.0009765625f;
          float var  = qs * 0.0009765625f - mean * mean;
          float rstd = rsqrtf(var + 1e-5f);
          if (pc < 126) {
            int row = w * 16 + lq * 4 + r;
            stcf(&p.predsT[(size_t)t * 8064 + row * 126 + pc],
                 rstd * (P[r] - mean * GsR) + BsR + pbr);
          }
        }
      }
      sigc(bar, S4G, i, t + 1);
    }
  }

  // ======== epilogue: predsT (t,n,m) -> out (n,m,t) ========
  waitc(bar, S4G, TSTEPS, 64);
  {
    float* trS = (float*)smem;
    for (int g = b; g < 504; g += 256) {
      int p0 = g * 16;
      for (int t0 = 0; t0 < 448; t0 += 16) {
        int tc = tid >> 4, pp = tid & 15;
        trS[tc * 17 + pp] = p.predsT[(size_t)(t0 + tc) * 8064 + p0 + pp];
        __syncthreads();
        p.out[(size_t)(p0 + (tid >> 4)) * 448 + t0 + (tid & 15)] = trS[(tid & 15) * 17 + (tid >> 4)];
        __syncthreads();
      }
    }
  }
}

// ---------------- host ----------------

extern "C" void kernel_launch(void* const* d_in, const int* in_sizes, int n_in,
                              void* d_out, int out_size, void* d_ws, size_t ws_size,
                              hipStream_t stream) {
  Ptrs p;
  p.aud = (const float*)d_in[0];
  p.mo  = (const float*)d_in[1];
  p.lxm = (const float*)d_in[2];
  p.vid = (const int*)d_in[3];
  p.eps = (const float*)d_in[4];
  p.csi_w0 = (const float*)d_in[5];  p.csi_b0 = (const float*)d_in[6];
  p.csi_w1 = (const float*)d_in[7];  p.csi_b1 = (const float*)d_in[8];
  p.csi_w2 = (const float*)d_in[9];  p.csi_b2 = (const float*)d_in[10];
  p.spk  = (const float*)d_in[11];
  p.mu_w = (const float*)d_in[12];   p.mu_b = (const float*)d_in[13];
  p.lv_w = (const float*)d_in[14];   p.lv_b = (const float*)d_in[15];
  p.embW = (const float*)d_in[16];   p.embB = (const float*)d_in[17];
  p.wih0 = (const float*)d_in[18];   p.whh0 = (const float*)d_in[19];
  p.bih0 = (const float*)d_in[20];   p.bhh0 = (const float*)d_in[21];
  p.wih1 = (const float*)d_in[22];   p.whh1 = (const float*)d_in[23];
  p.bih1 = (const float*)d_in[24];   p.bhh1 = (const float*)d_in[25];
  p.ln_g = (const float*)d_in[26];   p.ln_b = (const float*)d_in[27];
  p.predW = (const float*)d_in[28];  p.predB = (const float*)d_in[29];
  p.out = (float*)d_out;

  char* ws = (char*)d_ws;
  size_t off = 0;
  auto al = [&](size_t bytes) -> void* {
    void* r = (void*)(ws + off);
    off += (bytes + 255) & ~(size_t)255;
    return r;
  };
  p.bar    = (unsigned*)al(65536);
  p.mu5    = (float*)al(640);
  p.lv5    = (float*)al(640);
  p.gsbs   = (float*)al(1024);
  p.g2b2   = (float*)al(32768);
  p.h0F    = (float*)al(262144);
  p.h1F    = (float*)al(262144);
  p.h0B    = (f16*)al(131072);
  p.h1B    = (f16*)al(131072);
  p.ineB   = (f16*)al(131072);
  p.ghP0   = (float*)al(1048576);
  p.ghP1   = (float*)al(1048576);
  p.x0     = (float*)al(262144);
  p.x1     = (float*)al(262144);
  p.predsT = (float*)al(14450688);
  p.xcat   = (f16*)al(22020096);
  p.whh0P  = (f16*)al(6291456);
  p.whh1P  = (f16*)al(6291456);
  p.wih0aP = (f16*)al(6291456);
  p.wih0bP = (f16*)al(2359296);
  p.wih1P  = (f16*)al(6291456);
  p.embWP  = (f16*)al(786432);
  p.predWP = (f16*)al(262144);
  p.wcP    = (f16*)al(6291456);
  p.weP    = (f16*)al(2097152);

  k_init<<<64, 256, 0, stream>>>(p);

  k_pack<<<dim3(192, 32), 256, 0, stream>>>(p.whh0, p.whh0P, 1024, 0, 3072, 3072, nullptr);
  k_pack<<<dim3(192, 32), 256, 0, stream>>>(p.whh1, p.whh1P, 1024, 0, 3072, 3072, nullptr);
  k_pack<<<dim3(192, 32), 256, 0, stream>>>(p.wih0, p.wih0aP, 1024, 0, 3072, 3072, nullptr);
  k_pack<<<dim3(192, 12), 256, 0, stream>>>(p.wih0, p.wih0bP, 382, 1024, 3072, 3072, nullptr);
  k_pack<<<dim3(192, 32), 256, 0, stream>>>(p.wih1, p.wih1P, 1024, 0, 3072, 3072, nullptr);
  k_pack<<<dim3(64, 12), 256, 0, stream>>>(p.embW, p.embWP, 382, 0, 1024, 1024, nullptr);
  // predW packed with ln_g folded in (factored LayerNorm) — used by GH1 i<8
  k_pack<<<dim3(8, 32), 256, 0, stream>>>(p.predW, p.predWP, 1024, 0, 126, 126, p.ln_g);

  k_gsbs<<<1, 128, 0, stream>>>(p);
  k_g2b2<<<16, 256, 0, stream>>>(p);
  k_cwc<<<12288, 256, 0, stream>>>(p);
  k_cwe<<<4096, 256, 0, stream>>>(p);

  k_csi1<<<256, 256, 0, stream>>>(p);
  k_csi2<<<256, 256, 0, stream>>>(p);
  k_csi3<<<512, 256, 0, stream>>>(p);
  k_gh<<<1536, 256, 0, stream>>>(p);
  k_style1<<<1, 256, 0, stream>>>(p);
  k_style2<<<3584, 256, 0, stream>>>(p);
  k_aud<<<1792, 256, 0, stream>>>(p);
  k_lxm<<<10752, 256, 0, stream>>>(p);
  k_premo0<<<32, 256, 0, stream>>>(p);
  k_padz<<<224, 256, 0, stream>>>(p);
  k_zpred<<<7041, 256, 0, stream>>>(p);

  k_scan<<<256, 256, LDS_BYTES, stream>>>(p);

  (void)in_sizes; (void)n_in; (void)out_size; (void)ws_size;
}

// Round 9
// 14375.661 us; speedup vs baseline: 1.2327x; 1.2327x over previous
//
#include <hip/hip_runtime.h>
#include <cmath>

typedef _Float16 f16;
typedef _Float16 f16x8 __attribute__((ext_vector_type(8)));
typedef float f32x4 __attribute__((ext_vector_type(4)));
typedef unsigned long long u64;

#define MFMA_F16(a,b,c) __builtin_amdgcn_mfma_f32_16x16x32_f16((a),(b),(c),0,0,0)
#define AGENT __HIP_MEMORY_SCOPE_AGENT

// N=64, A=128, MO=126, LX=96, H=1024, S=32, P=2, B=16, BL=32, T=448
#define TSTEPS 448
#define OFF_MU 3612672   // 64*126*448
#define OFF_LV 4530176   // + 64*32*448
#define LDS_BYTES 156160

// signal classes (per-block flags: flag(cls, idx) = bar[(cls*64+idx)*32])
#define S1 0   // ineB ready        (64 signalers, idx b-64)
#define S2 1   // h0B ready         (64, idx b)
#define S3 2   // h1B ready         (64, idx b-64)
#define S3B 3  // gh0(t+1) ready    (64, idx b-128)
#define S4 4   // xcat(t+1)/pred    (8, idx b-64)
#define S4G 5  // gh1(t+1) ready    (64, idx b-192)

struct Ptrs {
  const float *aud, *mo, *lxm, *eps;
  const int *vid;
  const float *csi_w0, *csi_b0, *csi_w1, *csi_b1, *csi_w2, *csi_b2;
  const float *spk, *mu_w, *mu_b, *lv_w, *lv_b;
  const float *embW, *embB;
  const float *wih0, *whh0, *bih0, *bhh0;
  const float *wih1, *whh1, *bih1, *bhh1;
  const float *ln_g, *ln_b, *predW, *predB;
  float *out;
  unsigned *bar;
  float *mu5, *lv5, *h0F, *h1F, *gsbs;
  f16 *h0B, *h1B, *ineB, *xcat;
  float *ghP0, *ghP1, *x0, *x1, *predsT;
  f16 *whh0P, *whh1P, *wih0aP, *wih0bP, *wih1P, *embWP, *predWP;
};

__device__ __forceinline__ float geluf(float x) {
  return 0.5f * x * (1.0f + erff(x * 0.7071067811865475f));
}
// fast sigmoid/tanh: __expf + v_rcp (abs err ~1e-6, tolerance is 1.5e-2)
__device__ __forceinline__ float sigmf(float x) {
  return __builtin_amdgcn_rcpf(1.0f + __expf(-x));
}
__device__ __forceinline__ float tanhf_fast(float x) {
  float xc = fmaxf(x, -44.f);           // avoid exp overflow -> -inf*0 NaN
  float e = __expf(-2.f * xc);
  return (1.f - e) * __builtin_amdgcn_rcpf(1.f + e);
}

// ---- coherent (cross-XCD) primitives: compiler-visible, batchable ----
__device__ __forceinline__ u64 ldc8(const void* p) {
  return __hip_atomic_load((const u64*)p, __ATOMIC_RELAXED, AGENT);
}
__device__ __forceinline__ void stc8(void* p, u64 v) {
  __hip_atomic_store((u64*)p, v, __ATOMIC_RELAXED, AGENT);
}
__device__ __forceinline__ void stcf(float* p, float v) {
  __hip_atomic_store(p, v, __ATOMIC_RELAXED, AGENT);
}
__device__ __forceinline__ f16x8 toH(u64 a, u64 b) {
  union { u64 u[2]; f16x8 h; } r; r.u[0] = a; r.u[1] = b; return r.h;
}
__device__ __forceinline__ f32x4 toF(u64 a, u64 b) {
  union { u64 u[2]; f32x4 f; } r; r.u[0] = a; r.u[1] = b; return r.f;
}
__device__ __forceinline__ u64 packF2(float a, float b) {
  union { float f[2]; u64 u; } r; r.f[0] = a; r.f[1] = b; return r.u;
}
// pack (v, lane^1's v) into 2 f16 and store 4B coherently from even lanes
__device__ __forceinline__ void st_pair(f16* base, float v, int lm, bool pred) {
  float vn = __shfl_xor(v, 1);
  if (!(lm & 1) && pred) {
    union { f16 h[2]; unsigned u; } pk;
    pk.h[0] = (f16)v; pk.h[1] = (f16)vn;
    __hip_atomic_store((unsigned*)base, pk.u, __ATOMIC_RELAXED, AGENT);
  }
}

// ---------------- prologue kernels ----------------

__global__ void k_init(Ptrs p) {
  int gid = blockIdx.x * 256 + threadIdx.x;
  if (gid < 16384) p.bar[gid] = 0u;
}

__global__ void k_pack(const float* __restrict__ src, f16* __restrict__ dst,
                       int K, int rowOff, int realN, int ldN,
                       const float* __restrict__ scale) {
  int ct = blockIdx.x, kt = blockIdx.y;
  int e = threadIdx.x * 2;
  int l = e >> 3, i = e & 7;
  int k = kt * 32 + (l >> 4) * 8 + i;
  int col = ct * 16 + (l & 15);
  f16 v0 = (f16)0.f, v1 = (f16)0.f;
  if (k < K && col < realN) {
    float s = scale ? scale[rowOff + k] : 1.f;
    v0 = (f16)(src[(size_t)(rowOff + k) * ldN + col] * s);
  }
  if (k + 1 < K && col < realN) {
    float s = scale ? scale[rowOff + k + 1] : 1.f;
    v1 = (f16)(src[(size_t)(rowOff + k + 1) * ldN + col] * s);
  }
  size_t o = ((size_t)ct * gridDim.y + kt) * 512 + e;
  dst[o] = v0; dst[o + 1] = v1;
}

// Gs[m] = sum_k ln_g[k]*predW[k,m]; Bs[m] = sum_k ln_b[k]*predW[k,m]
__global__ void k_gsbs(Ptrs p) {
  int c = threadIdx.x;
  if (c < 126) {
    float gs = 0.f, bs = 0.f;
    for (int k = 0; k < 1024; k++) {
      float w = p.predW[(size_t)k * 126 + c];
      gs += p.ln_g[k] * w;
      bs += p.ln_b[k] * w;
    }
    p.gsbs[c] = gs; p.gsbs[128 + c] = bs;
  }
}

__global__ void k_csi1(Ptrs p) {
  int gid = blockIdx.x * 256 + threadIdx.x;  // 65536
  int n = gid >> 10, c = gid & 1023;
  float acc = p.csi_b0[c];
  const float* w = p.csi_w0 + c;
  for (int k = 0; k < 126; k++) acc += p.mo[((size_t)(n * 126 + k)) * 512 + 31] * w[(size_t)k * 1024];
  for (int k = 0; k < 96; k++)  acc += p.lxm[(size_t)(n * 96 + k) * 16] * w[(size_t)(126 + k) * 1024];
  p.x0[gid] = geluf(acc);
}

__global__ void k_csi2(Ptrs p) {
  int gid = blockIdx.x * 256 + threadIdx.x;
  int n = gid >> 10, c = gid & 1023;
  float acc = p.csi_b1[c];
  const float* w = p.csi_w1 + c;
  const float* x = p.x0 + (size_t)n * 1024;
  for (int k = 0; k < 1024; k++) acc += x[k] * w[(size_t)k * 1024];
  p.x1[gid] = geluf(acc);
}

__global__ void k_csi3(Ptrs p) {
  int gid = blockIdx.x * 256 + threadIdx.x;
  int n = gid >> 11, c2 = gid & 2047;
  float acc = p.csi_b2[c2];
  const float* w = p.csi_w2 + c2;
  const float* x = p.x1 + (size_t)n * 1024;
  for (int k = 0; k < 1024; k++) acc += x[k] * w[(size_t)k * 2048];
  if (c2 < 1024) { p.h0F[n * 1024 + c2] = acc; p.h0B[n * 1024 + c2] = (f16)acc; }
  else           { p.h1F[n * 1024 + c2 - 1024] = acc; p.h1B[n * 1024 + c2 - 1024] = (f16)acc; }
}

// initial gh0/gh1 for t=0, packed per-consumer-lane records:
// ghP[((ct*16+lm)*16 + w*4+lq)*16 + g*4 + r], row = w*16+lq*4+r, col = g*1024 + ct*16+lm
__global__ void k_gh(Ptrs p) {
  int gid = blockIdx.x * 256 + threadIdx.x;  // 393216
  int which = gid >= 196608;
  int g2 = which ? gid - 196608 : gid;
  int n = g2 / 3072, c = g2 % 3072;
  const float* h = which ? p.h1F : p.h0F;
  const float* W = which ? p.whh1 : p.whh0;
  const float* bb = which ? p.bhh1 : p.bhh0;
  float acc = bb[c];
  const float* hr = h + (size_t)n * 1024;
  for (int k = 0; k < 1024; k++) acc += hr[k] * W[(size_t)k * 3072 + c];
  int g = c >> 10, col = c & 1023;
  int ct = col >> 4, lm = col & 15, w = n >> 4, lq = (n >> 2) & 3, r = n & 3;
  float* dst = which ? p.ghP1 : p.ghP0;
  dst[((size_t)((ct * 16 + lm) * 16 + w * 4 + lq)) * 16 + g * 4 + r] = acc;
}

__global__ void k_style1(Ptrs p) {
  int tid = threadIdx.x;
  if (tid < 160) {
    int v = tid >> 5, s = tid & 31;
    float m = p.mu_b[s], lv = p.lv_b[s];
    for (int k = 0; k < 32; k++) {
      float z = p.spk[v * 32 + k];
      m += z * p.mu_w[k * 32 + s];
      lv += z * p.lv_w[k * 32 + s];
    }
    p.mu5[v * 32 + s] = m; p.lv5[v * 32 + s] = lv;
  }
}

__global__ void k_style2(Ptrs p) {
  int gid = blockIdx.x * 256 + threadIdx.x;  // 917504
  int t = gid % 448;
  int rr = gid / 448;
  int s = rr & 31, n = rr >> 5;
  int v = p.vid[n * 16 + (t >> 5) + 1];
  float mu = p.mu5[v * 32 + s], lv = p.lv5[v * 32 + s];
  float e = p.eps[((size_t)t * 64 + n) * 32 + s];
  float st = mu + e * expf(0.5f * lv);
  p.out[OFF_MU + ((size_t)n * 32 + s) * 448 + t] = mu;
  p.out[OFF_LV + ((size_t)n * 32 + s) * 448 + t] = lv;
  p.xcat[((size_t)t * 64 + n) * 384 + 350 + s] = (f16)st;
}

__global__ void k_aud(Ptrs p) {
  __shared__ float tile[32][65];
  int bid = blockIdx.x;  // 64*4*7
  int n = bid / 28, rem = bid % 28;
  int a0 = (rem / 7) * 32, t0 = (rem % 7) * 64;
  int tid = threadIdx.x;
  for (int i = tid; i < 2048; i += 256) {
    int ai = i >> 6, tj = i & 63;
    tile[ai][tj] = p.aud[((size_t)n * 128 + a0 + ai) * 448 + t0 + tj];
  }
  __syncthreads();
  for (int i = tid; i < 2048; i += 256) {
    int tj = i >> 5, ai = i & 31;
    p.xcat[((size_t)(t0 + tj) * 64 + n) * 384 + 126 + a0 + ai] = (f16)tile[ai][tj];
  }
}

__global__ void k_lxm(Ptrs p) {
  int gid = blockIdx.x * 256 + threadIdx.x;  // 2752512
  int l_ = gid % 96;
  int r = gid / 96;
  int n = r & 63, t = r >> 6;
  int tb = (t >> 5) + 1;
  p.xcat[((size_t)t * 64 + n) * 384 + 254 + l_] = (f16)p.lxm[((size_t)n * 96 + l_) * 16 + tb];
}

__global__ void k_premo0(Ptrs p) {
  int gid = blockIdx.x * 256 + threadIdx.x;
  if (gid < 8064) {
    int n = gid / 126, m = gid % 126;
    p.xcat[(size_t)n * 384 + m] = (f16)p.mo[((size_t)n * 126 + m) * 512 + 31];
  }
}

__global__ void k_padz(Ptrs p) {
  int gid = blockIdx.x * 256 + threadIdx.x;  // 57344
  int t = gid >> 7, rem = gid & 127;
  int n = rem >> 1, c = 382 + (rem & 1);
  p.xcat[((size_t)t * 64 + n) * 384 + c] = (f16)0.f;
}

// ---------------- persistent scan kernel ----------------

// signal: drain stores, then plain agent store of step value (one writer/flag)
__device__ __forceinline__ void sigc(unsigned* bar, int cls, int idx, unsigned val) {
  asm volatile("s_waitcnt vmcnt(0)" ::: "memory");
  __syncthreads();
  if (threadIdx.x == 0)
    __hip_atomic_store(&bar[(cls * 64 + idx) * 32], val, __ATOMIC_RELAXED, AGENT);
}
// busy-poll: 2 staggered poll streams per flag (halves detect quantization)
__device__ __forceinline__ void waitc(unsigned* bar, int cls, unsigned tgt, int nsig) {
  if (threadIdx.x < (unsigned)(2 * nsig)) {
    int sub = threadIdx.x & (nsig - 1);   // nsig is a power of 2 (8 or 64)
    const unsigned* f = &bar[(cls * 64 + sub) * 32];
    while (__hip_atomic_load(f, __ATOMIC_RELAXED, AGENT) < tgt) {}
  }
  __syncthreads();
}
// merged dual-class wait: cA has 8 signalers, cB has 64
__device__ __forceinline__ void waitc2(unsigned* bar, int cA, unsigned tA,
                                       int cB, unsigned tB) {
  if (threadIdx.x < 16) {
    const unsigned* f = &bar[(cA * 64 + (threadIdx.x & 7)) * 32];
    while (__hip_atomic_load(f, __ATOMIC_RELAXED, AGENT) < tA) {}
  } else if (threadIdx.x < 16 + 128) {
    int sub = (threadIdx.x - 16) & 63;
    const unsigned* f = &bar[(cB * 64 + sub) * 32];
    while (__hip_atomic_load(f, __ATOMIC_RELAXED, AGENT) < tB) {}
  }
  __syncthreads();
}

// pipelined 3-gate GEMM: A row coherent (batched u64 loads, double-buffered),
// weights LDS-resident at L+{0,16384,32768} (f16 offsets)
__device__ __forceinline__ void gemm3(const f16* aRow, const f16* L, int l,
                                      f32x4& A0, f32x4& A1, f32x4& A2) {
  const f16* w0 = L + l * 8;
  u64 ua[16], ub[16];
  #pragma unroll
  for (int j = 0; j < 8; j++) { ua[2*j] = ldc8(aRow + j * 32); ua[2*j+1] = ldc8(aRow + j * 32 + 4); }
  #pragma unroll
  for (int j = 0; j < 8; j++) { ub[2*j] = ldc8(aRow + 256 + j * 32); ub[2*j+1] = ldc8(aRow + 256 + j * 32 + 4); }
  #pragma unroll
  for (int j = 0; j < 8; j++) {
    f16x8 av = toH(ua[2*j], ua[2*j+1]);
    A0 = MFMA_F16(av, *(const f16x8*)(w0 + j * 512), A0);
    A1 = MFMA_F16(av, *(const f16x8*)(w0 + 16384 + j * 512), A1);
    A2 = MFMA_F16(av, *(const f16x8*)(w0 + 32768 + j * 512), A2);
  }
  #pragma unroll
  for (int j = 0; j < 8; j++) { ua[2*j] = ldc8(aRow + 512 + j * 32); ua[2*j+1] = ldc8(aRow + 512 + j * 32 + 4); }
  #pragma unroll
  for (int j = 0; j < 8; j++) {
    f16x8 av = toH(ub[2*j], ub[2*j+1]);
    int kt = 8 + j;
    A0 = MFMA_F16(av, *(const f16x8*)(w0 + kt * 512), A0);
    A1 = MFMA_F16(av, *(const f16x8*)(w0 + 16384 + kt * 512), A1);
    A2 = MFMA_F16(av, *(const f16x8*)(w0 + 32768 + kt * 512), A2);
  }
  #pragma unroll
  for (int j = 0; j < 8; j++) { ub[2*j] = ldc8(aRow + 768 + j * 32); ub[2*j+1] = ldc8(aRow + 768 + j * 32 + 4); }
  #pragma unroll
  for (int j = 0; j < 8; j++) {
    f16x8 av = toH(ua[2*j], ua[2*j+1]);
    int kt = 16 + j;
    A0 = MFMA_F16(av, *(const f16x8*)(w0 + kt * 512), A0);
    A1 = MFMA_F16(av, *(const f16x8*)(w0 + 16384 + kt * 512), A1);
    A2 = MFMA_F16(av, *(const f16x8*)(w0 + 32768 + kt * 512), A2);
  }
  #pragma unroll
  for (int j = 0; j < 8; j++) {
    f16x8 av = toH(ub[2*j], ub[2*j+1]);
    int kt = 24 + j;
    A0 = MFMA_F16(av, *(const f16x8*)(w0 + kt * 512), A0);
    A1 = MFMA_F16(av, *(const f16x8*)(w0 + 16384 + kt * 512), A1);
    A2 = MFMA_F16(av, *(const f16x8*)(w0 + 32768 + kt * 512), A2);
  }
}

__global__ __launch_bounds__(256, 1) void k_scan(Ptrs p) {
  extern __shared__ char smem[];
  f16* L = (f16*)smem;
  const int b = blockIdx.x, tid = threadIdx.x;
  const int w = tid >> 6, l = tid & 63;
  const int lm = l & 15, lq = l >> 4;

  // ---- one-time: stage weights into LDS (resident), preload biases ----
  {
    auto cp = [&](int dstF16, const f16* src, int nF16) {
      uint4* d = (uint4*)smem + (dstF16 >> 3);
      const uint4* s = (const uint4*)src;
      for (int i = tid; i < (nF16 >> 3); i += 256) d[i] = s[i];
    };
    if (b < 64) {
      cp(0,     p.wih0aP + (size_t)b * 16384, 16384);
      cp(16384, p.wih0aP + (size_t)(64 + b) * 16384, 16384);
      cp(32768, p.wih0aP + (size_t)(128 + b) * 16384, 16384);
      cp(49152, p.wih0bP + (size_t)b * 6144, 6144);
      cp(55296, p.wih0bP + (size_t)(64 + b) * 6144, 6144);
      cp(61440, p.wih0bP + (size_t)(128 + b) * 6144, 6144);
    } else if (b < 128) {
      int cb = b - 64;
      cp(0,     p.wih1P + (size_t)cb * 16384, 16384);
      cp(16384, p.wih1P + (size_t)(64 + cb) * 16384, 16384);
      cp(32768, p.wih1P + (size_t)(128 + cb) * 16384, 16384);
      cp(49152, p.embWP + (size_t)cb * 6144, 6144);
      if (cb < 8) cp(55296, p.predWP + (size_t)cb * 16384, 16384);
    } else if (b < 192) {
      int i = b - 128;
      cp(0,     p.whh0P + (size_t)i * 16384, 16384);
      cp(16384, p.whh0P + (size_t)(64 + i) * 16384, 16384);
      cp(32768, p.whh0P + (size_t)(128 + i) * 16384, 16384);
    } else {
      int i = b - 192;
      cp(0,     p.whh1P + (size_t)i * 16384, 16384);
      cp(16384, p.whh1P + (size_t)(64 + i) * 16384, 16384);
      cp(32768, p.whh1P + (size_t)(128 + i) * 16384, 16384);
    }
  }
  // per-lane constant biases + persistent GRU state (h0 or h1 slice in regs)
  float b0r = 0.f, b1r = 0.f, b2r = 0.f, ebr = 0.f, pbr = 0.f;
  float GsR = 0.f, BsR = 0.f;
  float hs[4] = {0.f, 0.f, 0.f, 0.f};
  if (b < 64) {
    int col = b * 16 + lm;
    b0r = p.bih0[col]; b1r = p.bih0[1024 + col]; b2r = p.bih0[2048 + col];
    #pragma unroll
    for (int r = 0; r < 4; r++) hs[r] = p.h0F[(size_t)(w * 16 + lq * 4 + r) * 1024 + col];
  } else if (b < 128) {
    int col = (b - 64) * 16 + lm;
    b0r = p.bih1[col]; b1r = p.bih1[1024 + col]; b2r = p.bih1[2048 + col];
    ebr = p.embB[col];
    #pragma unroll
    for (int r = 0; r < 4; r++) hs[r] = p.h1F[(size_t)(w * 16 + lq * 4 + r) * 1024 + col];
    if (b < 72 && col < 126) {
      pbr = p.predB[col];
      GsR = p.gsbs[col];
      BsR = p.gsbs[128 + col];
    }
  } else if (b < 192) {
    int col = (b - 128) * 16 + lm;
    b0r = p.bhh0[col]; b1r = p.bhh0[1024 + col]; b2r = p.bhh0[2048 + col];
  } else {
    int col = (b - 192) * 16 + lm;
    b0r = p.bhh1[col]; b1r = p.bhh1[1024 + col]; b2r = p.bhh1[2048 + col];
  }
  __syncthreads();

  unsigned* bar = p.bar;

  for (unsigned t = 0; t < TSTEPS; t++) {
    const f16* xc = p.xcat + (size_t)t * 24576;

    if (b < 64) {
      // ================= BB: gip (static + dyn) then h0n =================
      f32x4 a0 = {0,0,0,0}, a1 = {0,0,0,0}, a2 = {0,0,0,0};
      const f16* aB = xc + (w * 16 + lm) * 384 + lq * 8;
      const f16* wl = L + 49152 + l * 8;
      #pragma unroll
      for (int kt = 4; kt < 12; kt++) {
        f16x8 av = *(const f16x8*)(aB + kt * 32);
        a0 = MFMA_F16(av, *(const f16x8*)(wl + kt * 512), a0);
        a1 = MFMA_F16(av, *(const f16x8*)(wl + 6144 + kt * 512), a1);
        a2 = MFMA_F16(av, *(const f16x8*)(wl + 12288 + kt * 512), a2);
      }
      // S3B(t) is produced 2 segments before S4(t) (GH0 runs in step t-1's
      // slack) — merge its check into the S4 wait and issue the ghP0 record
      // loads immediately, so their latency hides under the gip-dyn phase.
      if (t) waitc2(bar, S4, t, S3B, t);
      const float* rec = p.ghP0 + ((size_t)((b * 16 + lm) * 16 + w * 4 + lq)) * 16;
      u64 r0 = ldc8(rec), r1 = ldc8(rec + 2), r2 = ldc8(rec + 4);
      u64 r3 = ldc8(rec + 6), r4 = ldc8(rec + 8), r5 = ldc8(rec + 10);
      f32x4 gip0, gip1, gip2;
      {
        u64 up[8];
        #pragma unroll
        for (int kt = 0; kt < 4; kt++) { up[2*kt] = ldc8(aB + kt * 32); up[2*kt+1] = ldc8(aB + kt * 32 + 4); }
        #pragma unroll
        for (int kt = 0; kt < 4; kt++) {
          f16x8 av = toH(up[2*kt], up[2*kt+1]);
          a0 = MFMA_F16(av, *(const f16x8*)(wl + kt * 512), a0);
          a1 = MFMA_F16(av, *(const f16x8*)(wl + 6144 + kt * 512), a1);
          a2 = MFMA_F16(av, *(const f16x8*)(wl + 12288 + kt * 512), a2);
        }
        #pragma unroll
        for (int r = 0; r < 4; r++) {
          gip0[r] = a0[r] + b0r; gip1[r] = a1[r] + b1r; gip2[r] = a2[r] + b2r;
        }
      }
      waitc(bar, S1, t + 1, 64);
      {
        f32x4 A0 = {0,0,0,0}, A1 = {0,0,0,0}, A2 = {0,0,0,0};
        gemm3(p.ineB + (w * 16 + lm) * 1024 + lq * 8, L, l, A0, A1, A2);
        f32x4 g0 = toF(r0, r1), g1 = toF(r2, r3), g2 = toF(r4, r5);
        int col = b * 16 + lm;
        #pragma unroll
        for (int r = 0; r < 4; r++) {
          int row = w * 16 + lq * 4 + r;
          float r_ = sigmf(A0[r] + gip0[r] + g0[r]);
          float z_ = sigmf(A1[r] + gip1[r] + g1[r]);
          float n_ = tanhf_fast(A2[r] + gip2[r] + r_ * g2[r]);
          float hn = (1.f - z_) * n_ + z_ * hs[r];
          hs[r] = hn;
          st_pair(p.h0B + (size_t)row * 1024 + col, hn, lm, true);
        }
      }
      sigc(bar, S2, b, t + 1);
    } else if (b < 128) {
      // ================= CB: ine then h1n; cb<8 also pred =================
      int cb = b - 64;
      int col = cb * 16 + lm;
      // static ine k-tiles before S4 wait
      f32x4 acc = {0,0,0,0};
      const f16* aB = xc + (w * 16 + lm) * 384 + lq * 8;
      const f16* wl = L + 49152 + l * 8;
      #pragma unroll
      for (int kt = 4; kt < 12; kt++)
        acc = MFMA_F16(*(const f16x8*)(aB + kt * 32), *(const f16x8*)(wl + kt * 512), acc);
      if (t) waitc(bar, S4, t, 8);
      {
        u64 up[8];
        #pragma unroll
        for (int kt = 0; kt < 4; kt++) { up[2*kt] = ldc8(aB + kt * 32); up[2*kt+1] = ldc8(aB + kt * 32 + 4); }
        #pragma unroll
        for (int kt = 0; kt < 4; kt++)
          acc = MFMA_F16(toH(up[2*kt], up[2*kt+1]), *(const f16x8*)(wl + kt * 512), acc);
        #pragma unroll
        for (int r = 0; r < 4; r++) {
          int row = w * 16 + lq * 4 + r;
          float v = geluf(acc[r] + ebr);
          st_pair(p.ineB + (size_t)row * 1024 + col, v, lm, true);
        }
      }
      sigc(bar, S1, cb, t + 1);
      // gh1(t) off-path: confirm flag, issue record loads, then wait h0 (S2)
      waitc(bar, S4G, t, 64);
      const float* rec = p.ghP1 + ((size_t)((cb * 16 + lm) * 16 + w * 4 + lq)) * 16;
      u64 r0 = ldc8(rec), r1 = ldc8(rec + 2), r2 = ldc8(rec + 4);
      u64 r3 = ldc8(rec + 6), r4 = ldc8(rec + 8), r5 = ldc8(rec + 10);
      waitc(bar, S2, t + 1, 64);
      {
        f32x4 A0 = {0,0,0,0}, A1 = {0,0,0,0}, A2 = {0,0,0,0};
        gemm3(p.h0B + (w * 16 + lm) * 1024 + lq * 8, L, l, A0, A1, A2);
        f32x4 g0 = toF(r0, r1), g1 = toF(r2, r3), g2 = toF(r4, r5);
        #pragma unroll
        for (int r = 0; r < 4; r++) {
          int row = w * 16 + lq * 4 + r;
          float r_ = sigmf(A0[r] + b0r + g0[r]);
          float z_ = sigmf(A1[r] + b1r + g1[r]);
          float n_ = tanhf_fast(A2[r] + b2r + r_ * g2[r]);
          float hn = (1.f - z_) * n_ + z_ * hs[r];
          hs[r] = hn;
          st_pair(p.h1B + (size_t)row * 1024 + col, hn, lm, true);
        }
      }
      sigc(bar, S3, cb, t + 1);
      if (cb < 8) {
        // ---- pred: factored LayerNorm. GEMM uses raw h1B (ln_g folded into
        // predW'); LN stats computed IN-GEMM from the same loaded registers.
        // predsT stores deferred past the S4 signal (off critical drain) ----
        waitc(bar, S3, t + 1, 64);
        int myrow = w * 16 + lm;
        f32x4 pacc = {0,0,0,0};
        const f16* hB = p.h1B + (size_t)myrow * 1024 + lq * 8;
        const f16* wp = L + 55296 + l * 8;
        u64 ua[16], ub[16];
        float ssum = 0.f, ssq = 0.f;
        #pragma unroll
        for (int j = 0; j < 8; j++) { ua[2*j] = ldc8(hB + j * 32); ua[2*j+1] = ldc8(hB + j * 32 + 4); }
        #pragma unroll
        for (int j = 0; j < 8; j++) { ub[2*j] = ldc8(hB + 256 + j * 32); ub[2*j+1] = ldc8(hB + 256 + j * 32 + 4); }
        auto compP = [&](u64* cur, int g) {
          #pragma unroll
          for (int j = 0; j < 8; j++) {
            int kt = g * 8 + j;
            f16x8 hv = toH(cur[2*j], cur[2*j+1]);
            pacc = MFMA_F16(hv, *(const f16x8*)(wp + kt * 512), pacc);
            #pragma unroll
            for (int e = 0; e < 8; e++) {
              float v = (float)hv[e];
              ssum += v; ssq += v * v;
            }
          }
        };
        compP(ua, 0);
        #pragma unroll
        for (int j = 0; j < 8; j++) { ua[2*j] = ldc8(hB + 512 + j * 32); ua[2*j+1] = ldc8(hB + 512 + j * 32 + 4); }
        compP(ub, 1);
        #pragma unroll
        for (int j = 0; j < 8; j++) { ub[2*j] = ldc8(hB + 768 + j * 32); ub[2*j+1] = ldc8(hB + 768 + j * 32 + 4); }
        compP(ua, 2);
        compP(ub, 3);
        // stats for row myrow: reduce over the lq-group (lanes lm, lm+16, lm+32, lm+48)
        ssum += __shfl_xor(ssum, 16); ssq += __shfl_xor(ssq, 16);
        ssum += __shfl_xor(ssum, 32); ssq += __shfl_xor(ssq, 32);
        float outv[4];
        #pragma unroll
        for (int r = 0; r < 4; r++) {
          int row = w * 16 + lq * 4 + r;
          int src = (l & 48) | (lq * 4 + r);   // lane (same lq group) holding row's stats
          float ms = __shfl(ssum, src);
          float qs = __shfl(ssq, src);
          float mean = ms * 0.0009765625f;
          float var  = qs * 0.0009765625f - mean * mean;
          float rstd = rsqrtf(var + 1e-5f);
          float v = rstd * (pacc[r] - mean * GsR) + BsR + pbr;
          outv[r] = v;
          st_pair(p.xcat + (size_t)(t + 1) * 24576 + row * 384 + col, v, lm,
                  col < 126 && t < 447);
        }
        if (t == 447 && col < 126) {   // final step: predsT must drain before S4
          #pragma unroll
          for (int r = 0; r < 4; r++)
            stcf(&p.predsT[(size_t)t * 8064 + (w * 16 + lq * 4 + r) * 126 + col], outv[r]);
        }
        sigc(bar, S4, cb, t + 1);
        if (t < 447 && col < 126) {    // off-path: drained by next iteration's S1 sigc
          #pragma unroll
          for (int r = 0; r < 4; r++)
            stcf(&p.predsT[(size_t)t * 8064 + (w * 16 + lq * 4 + r) * 126 + col], outv[r]);
        }
      }
    } else if (b < 192) {
      // ================= GH0: gh0(t+1) =================
      int i = b - 128;
      waitc(bar, S2, t + 1, 64);
      {
        f32x4 A0 = {0,0,0,0}, A1 = {0,0,0,0}, A2 = {0,0,0,0};
        gemm3(p.h0B + (w * 16 + lm) * 1024 + lq * 8, L, l, A0, A1, A2);
        float* rec = p.ghP0 + ((size_t)((i * 16 + lm) * 16 + w * 4 + lq)) * 16;
        stc8(rec,      packF2(A0[0] + b0r, A0[1] + b0r));
        stc8(rec + 2,  packF2(A0[2] + b0r, A0[3] + b0r));
        stc8(rec + 4,  packF2(A1[0] + b1r, A1[1] + b1r));
        stc8(rec + 6,  packF2(A1[2] + b1r, A1[3] + b1r));
        stc8(rec + 8,  packF2(A2[0] + b2r, A2[1] + b2r));
        stc8(rec + 10, packF2(A2[2] + b2r, A2[3] + b2r));
      }
      sigc(bar, S3B, i, t + 1);
    } else {
      // ================= GH1: gh1(t+1) =================
      int i = b - 192;
      waitc(bar, S3, t + 1, 64);
      {
        f32x4 A0 = {0,0,0,0}, A1 = {0,0,0,0}, A2 = {0,0,0,0};
        gemm3(p.h1B + (w * 16 + lm) * 1024 + lq * 8, L, l, A0, A1, A2);
        float* rec = p.ghP1 + ((size_t)((i * 16 + lm) * 16 + w * 4 + lq)) * 16;
        stc8(rec,      packF2(A0[0] + b0r, A0[1] + b0r));
        stc8(rec + 2,  packF2(A0[2] + b0r, A0[3] + b0r));
        stc8(rec + 4,  packF2(A1[0] + b1r, A1[1] + b1r));
        stc8(rec + 6,  packF2(A1[2] + b1r, A1[3] + b1r));
        stc8(rec + 8,  packF2(A2[0] + b2r, A2[1] + b2r));
        stc8(rec + 10, packF2(A2[2] + b2r, A2[3] + b2r));
      }
      sigc(bar, S4G, i, t + 1);
    }
  }

  // ======== epilogue: predsT (t,n,m) -> out (n,m,t) ========
  waitc(bar, S4, TSTEPS, 8);
  {
    float* trS = (float*)smem;
    for (int g = b; g < 504; g += 256) {
      int p0 = g * 16;
      for (int t0 = 0; t0 < 448; t0 += 16) {
        int tc = tid >> 4, pp = tid & 15;
        trS[tc * 17 + pp] = p.predsT[(size_t)(t0 + tc) * 8064 + p0 + pp];
        __syncthreads();
        p.out[(size_t)(p0 + (tid >> 4)) * 448 + t0 + (tid & 15)] = trS[(tid & 15) * 17 + (tid >> 4)];
        __syncthreads();
      }
    }
  }
}

// ---------------- host ----------------

extern "C" void kernel_launch(void* const* d_in, const int* in_sizes, int n_in,
                              void* d_out, int out_size, void* d_ws, size_t ws_size,
                              hipStream_t stream) {
  Ptrs p;
  p.aud = (const float*)d_in[0];
  p.mo  = (const float*)d_in[1];
  p.lxm = (const float*)d_in[2];
  p.vid = (const int*)d_in[3];
  p.eps = (const float*)d_in[4];
  p.csi_w0 = (const float*)d_in[5];  p.csi_b0 = (const float*)d_in[6];
  p.csi_w1 = (const float*)d_in[7];  p.csi_b1 = (const float*)d_in[8];
  p.csi_w2 = (const float*)d_in[9];  p.csi_b2 = (const float*)d_in[10];
  p.spk  = (const float*)d_in[11];
  p.mu_w = (const float*)d_in[12];   p.mu_b = (const float*)d_in[13];
  p.lv_w = (const float*)d_in[14];   p.lv_b = (const float*)d_in[15];
  p.embW = (const float*)d_in[16];   p.embB = (const float*)d_in[17];
  p.wih0 = (const float*)d_in[18];   p.whh0 = (const float*)d_in[19];
  p.bih0 = (const float*)d_in[20];   p.bhh0 = (const float*)d_in[21];
  p.wih1 = (const float*)d_in[22];   p.whh1 = (const float*)d_in[23];
  p.bih1 = (const float*)d_in[24];   p.bhh1 = (const float*)d_in[25];
  p.ln_g = (const float*)d_in[26];   p.ln_b = (const float*)d_in[27];
  p.predW = (const float*)d_in[28];  p.predB = (const float*)d_in[29];
  p.out = (float*)d_out;

  char* ws = (char*)d_ws;
  size_t off = 0;
  auto al = [&](size_t bytes) -> void* {
    void* r = (void*)(ws + off);
    off += (bytes + 255) & ~(size_t)255;
    return r;
  };
  p.bar    = (unsigned*)al(65536);
  p.mu5    = (float*)al(640);
  p.lv5    = (float*)al(640);
  p.gsbs   = (float*)al(1024);
  p.h0F    = (float*)al(262144);
  p.h1F    = (float*)al(262144);
  p.h0B    = (f16*)al(131072);
  p.h1B    = (f16*)al(131072);
  p.ineB   = (f16*)al(131072);
  p.ghP0   = (float*)al(1048576);
  p.ghP1   = (float*)al(1048576);
  p.x0     = (float*)al(262144);
  p.x1     = (float*)al(262144);
  p.predsT = (float*)al(14450688);
  p.xcat   = (f16*)al(22020096);
  p.whh0P  = (f16*)al(6291456);
  p.whh1P  = (f16*)al(6291456);
  p.wih0aP = (f16*)al(6291456);
  p.wih0bP = (f16*)al(2359296);
  p.wih1P  = (f16*)al(6291456);
  p.embWP  = (f16*)al(786432);
  p.predWP = (f16*)al(262144);

  k_init<<<64, 256, 0, stream>>>(p);

  k_pack<<<dim3(192, 32), 256, 0, stream>>>(p.whh0, p.whh0P, 1024, 0, 3072, 3072, nullptr);
  k_pack<<<dim3(192, 32), 256, 0, stream>>>(p.whh1, p.whh1P, 1024, 0, 3072, 3072, nullptr);
  k_pack<<<dim3(192, 32), 256, 0, stream>>>(p.wih0, p.wih0aP, 1024, 0, 3072, 3072, nullptr);
  k_pack<<<dim3(192, 12), 256, 0, stream>>>(p.wih0, p.wih0bP, 382, 1024, 3072, 3072, nullptr);
  k_pack<<<dim3(192, 32), 256, 0, stream>>>(p.wih1, p.wih1P, 1024, 0, 3072, 3072, nullptr);
  k_pack<<<dim3(64, 12), 256, 0, stream>>>(p.embW, p.embWP, 382, 0, 1024, 1024, nullptr);
  // predW packed with ln_g folded in (factored LayerNorm)
  k_pack<<<dim3(8, 32), 256, 0, stream>>>(p.predW, p.predWP, 1024, 0, 126, 126, p.ln_g);

  k_gsbs<<<1, 128, 0, stream>>>(p);
  k_csi1<<<256, 256, 0, stream>>>(p);
  k_csi2<<<256, 256, 0, stream>>>(p);
  k_csi3<<<512, 256, 0, stream>>>(p);
  k_gh<<<1536, 256, 0, stream>>>(p);
  k_style1<<<1, 256, 0, stream>>>(p);
  k_style2<<<3584, 256, 0, stream>>>(p);
  k_aud<<<1792, 256, 0, stream>>>(p);
  k_lxm<<<10752, 256, 0, stream>>>(p);
  k_premo0<<<32, 256, 0, stream>>>(p);
  k_padz<<<224, 256, 0, stream>>>(p);

  k_scan<<<256, 256, LDS_BYTES, stream>>>(p);

  (void)in_sizes; (void)n_in; (void)out_size; (void)ws_size;
}

// Round 10
// 14348.425 us; speedup vs baseline: 1.2351x; 1.0019x over previous
//
#include <hip/hip_runtime.h>
#include <cmath>

typedef _Float16 f16;
typedef _Float16 f16x8 __attribute__((ext_vector_type(8)));
typedef float f32x4 __attribute__((ext_vector_type(4)));
typedef unsigned long long u64;

#define MFMA_F16(a,b,c) __builtin_amdgcn_mfma_f32_16x16x32_f16((a),(b),(c),0,0,0)
#define AGENT __HIP_MEMORY_SCOPE_AGENT

// N=64, A=128, MO=126, LX=96, H=1024, S=32, P=2, B=16, BL=32, T=448
#define TSTEPS 448
#define OFF_MU 3612672   // 64*126*448
#define OFF_LV 4530176   // + 64*32*448
#define LDS_BYTES 156160

// signal classes (per-block flags: flag(cls, idx) = bar[(cls*64+idx)*32])
#define S1 0   // ineB ready        (64 signalers, idx b-64)
#define S2 1   // h0B ready         (64, idx b)
#define S3 2   // h1B ready         (64, idx b-64)
#define S3B 3  // gh0(t+1) ready    (64, idx b-128)
#define S4 4   // xcat(t+1)/pred    (8, idx b-64)
#define S4G 5  // gh1(t+1) ready    (64, idx b-192)

struct Ptrs {
  const float *aud, *mo, *lxm, *eps;
  const int *vid;
  const float *csi_w0, *csi_b0, *csi_w1, *csi_b1, *csi_w2, *csi_b2;
  const float *spk, *mu_w, *mu_b, *lv_w, *lv_b;
  const float *embW, *embB;
  const float *wih0, *whh0, *bih0, *bhh0;
  const float *wih1, *whh1, *bih1, *bhh1;
  const float *ln_g, *ln_b, *predW, *predB;
  float *out;
  unsigned *bar;
  float *mu5, *lv5, *h0F, *h1F, *gsbs;
  f16 *h0B, *h1B, *ineB, *xcat;
  float *ghP0, *ghP1, *x0, *x1, *predsT;
  f16 *whh0P, *whh1P, *wih0aP, *wih0bP, *wih1P, *embWP, *predWP;
};

__device__ __forceinline__ float geluf(float x) {
  return 0.5f * x * (1.0f + erff(x * 0.7071067811865475f));
}
// fast sigmoid/tanh: __expf + v_rcp (abs err ~1e-6, tolerance is 1.5e-2)
__device__ __forceinline__ float sigmf(float x) {
  return __builtin_amdgcn_rcpf(1.0f + __expf(-x));
}
__device__ __forceinline__ float tanhf_fast(float x) {
  float xc = fmaxf(x, -44.f);           // avoid exp overflow -> -inf*0 NaN
  float e = __expf(-2.f * xc);
  return (1.f - e) * __builtin_amdgcn_rcpf(1.f + e);
}

// ---- coherent (cross-XCD) primitives: compiler-visible, batchable ----
__device__ __forceinline__ u64 ldc8(const void* p) {
  return __hip_atomic_load((const u64*)p, __ATOMIC_RELAXED, AGENT);
}
__device__ __forceinline__ void stc8(void* p, u64 v) {
  __hip_atomic_store((u64*)p, v, __ATOMIC_RELAXED, AGENT);
}
__device__ __forceinline__ void stcf(float* p, float v) {
  __hip_atomic_store(p, v, __ATOMIC_RELAXED, AGENT);
}
__device__ __forceinline__ f16x8 toH(u64 a, u64 b) {
  union { u64 u[2]; f16x8 h; } r; r.u[0] = a; r.u[1] = b; return r.h;
}
__device__ __forceinline__ f32x4 toF(u64 a, u64 b) {
  union { u64 u[2]; f32x4 f; } r; r.u[0] = a; r.u[1] = b; return r.f;
}
__device__ __forceinline__ u64 packF2(float a, float b) {
  union { float f[2]; u64 u; } r; r.f[0] = a; r.f[1] = b; return r.u;
}
// pack (v, lane^1's v) into 2 f16 and store 4B coherently from even lanes
__device__ __forceinline__ void st_pair(f16* base, float v, int lm, bool pred) {
  float vn = __shfl_xor(v, 1);
  if (!(lm & 1) && pred) {
    union { f16 h[2]; unsigned u; } pk;
    pk.h[0] = (f16)v; pk.h[1] = (f16)vn;
    __hip_atomic_store((unsigned*)base, pk.u, __ATOMIC_RELAXED, AGENT);
  }
}

// ---------------- prologue kernels ----------------

__global__ void k_init(Ptrs p) {
  int gid = blockIdx.x * 256 + threadIdx.x;
  if (gid < 16384) p.bar[gid] = 0u;
}

__global__ void k_pack(const float* __restrict__ src, f16* __restrict__ dst,
                       int K, int rowOff, int realN, int ldN,
                       const float* __restrict__ scale) {
  int ct = blockIdx.x, kt = blockIdx.y;
  int e = threadIdx.x * 2;
  int l = e >> 3, i = e & 7;
  int k = kt * 32 + (l >> 4) * 8 + i;
  int col = ct * 16 + (l & 15);
  f16 v0 = (f16)0.f, v1 = (f16)0.f;
  if (k < K && col < realN) {
    float s = scale ? scale[rowOff + k] : 1.f;
    v0 = (f16)(src[(size_t)(rowOff + k) * ldN + col] * s);
  }
  if (k + 1 < K && col < realN) {
    float s = scale ? scale[rowOff + k + 1] : 1.f;
    v1 = (f16)(src[(size_t)(rowOff + k + 1) * ldN + col] * s);
  }
  size_t o = ((size_t)ct * gridDim.y + kt) * 512 + e;
  dst[o] = v0; dst[o + 1] = v1;
}

// Gs[m] = sum_k ln_g[k]*predW[k,m]; Bs[m] = sum_k ln_b[k]*predW[k,m]
__global__ void k_gsbs(Ptrs p) {
  int c = threadIdx.x;
  if (c < 126) {
    float gs = 0.f, bs = 0.f;
    for (int k = 0; k < 1024; k++) {
      float w = p.predW[(size_t)k * 126 + c];
      gs += p.ln_g[k] * w;
      bs += p.ln_b[k] * w;
    }
    p.gsbs[c] = gs; p.gsbs[128 + c] = bs;
  }
}

__global__ void k_csi1(Ptrs p) {
  int gid = blockIdx.x * 256 + threadIdx.x;  // 65536
  int n = gid >> 10, c = gid & 1023;
  float acc = p.csi_b0[c];
  const float* w = p.csi_w0 + c;
  for (int k = 0; k < 126; k++) acc += p.mo[((size_t)(n * 126 + k)) * 512 + 31] * w[(size_t)k * 1024];
  for (int k = 0; k < 96; k++)  acc += p.lxm[(size_t)(n * 96 + k) * 16] * w[(size_t)(126 + k) * 1024];
  p.x0[gid] = geluf(acc);
}

__global__ void k_csi2(Ptrs p) {
  int gid = blockIdx.x * 256 + threadIdx.x;
  int n = gid >> 10, c = gid & 1023;
  float acc = p.csi_b1[c];
  const float* w = p.csi_w1 + c;
  const float* x = p.x0 + (size_t)n * 1024;
  for (int k = 0; k < 1024; k++) acc += x[k] * w[(size_t)k * 1024];
  p.x1[gid] = geluf(acc);
}

__global__ void k_csi3(Ptrs p) {
  int gid = blockIdx.x * 256 + threadIdx.x;
  int n = gid >> 11, c2 = gid & 2047;
  float acc = p.csi_b2[c2];
  const float* w = p.csi_w2 + c2;
  const float* x = p.x1 + (size_t)n * 1024;
  for (int k = 0; k < 1024; k++) acc += x[k] * w[(size_t)k * 2048];
  if (c2 < 1024) { p.h0F[n * 1024 + c2] = acc; p.h0B[n * 1024 + c2] = (f16)acc; }
  else           { p.h1F[n * 1024 + c2 - 1024] = acc; p.h1B[n * 1024 + c2 - 1024] = (f16)acc; }
}

// initial gh0/gh1 for t=0, packed per-consumer-lane records:
// ghP[((ct*16+lm)*16 + w*4+lq)*16 + g*4 + r], row = w*16+lq*4+r, col = g*1024 + ct*16+lm
__global__ void k_gh(Ptrs p) {
  int gid = blockIdx.x * 256 + threadIdx.x;  // 393216
  int which = gid >= 196608;
  int g2 = which ? gid - 196608 : gid;
  int n = g2 / 3072, c = g2 % 3072;
  const float* h = which ? p.h1F : p.h0F;
  const float* W = which ? p.whh1 : p.whh0;
  const float* bb = which ? p.bhh1 : p.bhh0;
  float acc = bb[c];
  const float* hr = h + (size_t)n * 1024;
  for (int k = 0; k < 1024; k++) acc += hr[k] * W[(size_t)k * 3072 + c];
  int g = c >> 10, col = c & 1023;
  int ct = col >> 4, lm = col & 15, w = n >> 4, lq = (n >> 2) & 3, r = n & 3;
  float* dst = which ? p.ghP1 : p.ghP0;
  dst[((size_t)((ct * 16 + lm) * 16 + w * 4 + lq)) * 16 + g * 4 + r] = acc;
}

__global__ void k_style1(Ptrs p) {
  int tid = threadIdx.x;
  if (tid < 160) {
    int v = tid >> 5, s = tid & 31;
    float m = p.mu_b[s], lv = p.lv_b[s];
    for (int k = 0; k < 32; k++) {
      float z = p.spk[v * 32 + k];
      m += z * p.mu_w[k * 32 + s];
      lv += z * p.lv_w[k * 32 + s];
    }
    p.mu5[v * 32 + s] = m; p.lv5[v * 32 + s] = lv;
  }
}

__global__ void k_style2(Ptrs p) {
  int gid = blockIdx.x * 256 + threadIdx.x;  // 917504
  int t = gid % 448;
  int rr = gid / 448;
  int s = rr & 31, n = rr >> 5;
  int v = p.vid[n * 16 + (t >> 5) + 1];
  float mu = p.mu5[v * 32 + s], lv = p.lv5[v * 32 + s];
  float e = p.eps[((size_t)t * 64 + n) * 32 + s];
  float st = mu + e * expf(0.5f * lv);
  p.out[OFF_MU + ((size_t)n * 32 + s) * 448 + t] = mu;
  p.out[OFF_LV + ((size_t)n * 32 + s) * 448 + t] = lv;
  p.xcat[((size_t)t * 64 + n) * 384 + 350 + s] = (f16)st;
}

__global__ void k_aud(Ptrs p) {
  __shared__ float tile[32][65];
  int bid = blockIdx.x;  // 64*4*7
  int n = bid / 28, rem = bid % 28;
  int a0 = (rem / 7) * 32, t0 = (rem % 7) * 64;
  int tid = threadIdx.x;
  for (int i = tid; i < 2048; i += 256) {
    int ai = i >> 6, tj = i & 63;
    tile[ai][tj] = p.aud[((size_t)n * 128 + a0 + ai) * 448 + t0 + tj];
  }
  __syncthreads();
  for (int i = tid; i < 2048; i += 256) {
    int tj = i >> 5, ai = i & 31;
    p.xcat[((size_t)(t0 + tj) * 64 + n) * 384 + 126 + a0 + ai] = (f16)tile[ai][tj];
  }
}

__global__ void k_lxm(Ptrs p) {
  int gid = blockIdx.x * 256 + threadIdx.x;  // 2752512
  int l_ = gid % 96;
  int r = gid / 96;
  int n = r & 63, t = r >> 6;
  int tb = (t >> 5) + 1;
  p.xcat[((size_t)t * 64 + n) * 384 + 254 + l_] = (f16)p.lxm[((size_t)n * 96 + l_) * 16 + tb];
}

__global__ void k_premo0(Ptrs p) {
  int gid = blockIdx.x * 256 + threadIdx.x;
  if (gid < 8064) {
    int n = gid / 126, m = gid % 126;
    p.xcat[(size_t)n * 384 + m] = (f16)p.mo[((size_t)n * 126 + m) * 512 + 31];
  }
}

__global__ void k_padz(Ptrs p) {
  int gid = blockIdx.x * 256 + threadIdx.x;  // 57344
  int t = gid >> 7, rem = gid & 127;
  int n = rem >> 1, c = 382 + (rem & 1);
  p.xcat[((size_t)t * 64 + n) * 384 + c] = (f16)0.f;
}

// ---------------- persistent scan kernel ----------------

// signal: drain stores, then plain agent store of step value (one writer/flag)
__device__ __forceinline__ void sigc(unsigned* bar, int cls, int idx, unsigned val) {
  asm volatile("s_waitcnt vmcnt(0)" ::: "memory");
  __syncthreads();
  if (threadIdx.x == 0)
    __hip_atomic_store(&bar[(cls * 64 + idx) * 32], val, __ATOMIC_RELAXED, AGENT);
}
// busy-poll: nsig lanes each watch one producer's flag
__device__ __forceinline__ void waitc(unsigned* bar, int cls, unsigned tgt, int nsig) {
  if (threadIdx.x < (unsigned)nsig) {
    const unsigned* f = &bar[(cls * 64 + threadIdx.x) * 32];
    while (__hip_atomic_load(f, __ATOMIC_RELAXED, AGENT) < tgt) {}
  }
  __syncthreads();
}

// pipelined 3-gate GEMM: A row coherent (batched u64 loads, double-buffered),
// weights LDS-resident at L+{0,16384,32768} (f16 offsets)
__device__ __forceinline__ void gemm3(const f16* aRow, const f16* L, int l,
                                      f32x4& A0, f32x4& A1, f32x4& A2) {
  const f16* w0 = L + l * 8;
  u64 ua[16], ub[16];
  #pragma unroll
  for (int j = 0; j < 8; j++) { ua[2*j] = ldc8(aRow + j * 32); ua[2*j+1] = ldc8(aRow + j * 32 + 4); }
  #pragma unroll
  for (int j = 0; j < 8; j++) { ub[2*j] = ldc8(aRow + 256 + j * 32); ub[2*j+1] = ldc8(aRow + 256 + j * 32 + 4); }
  #pragma unroll
  for (int j = 0; j < 8; j++) {
    f16x8 av = toH(ua[2*j], ua[2*j+1]);
    A0 = MFMA_F16(av, *(const f16x8*)(w0 + j * 512), A0);
    A1 = MFMA_F16(av, *(const f16x8*)(w0 + 16384 + j * 512), A1);
    A2 = MFMA_F16(av, *(const f16x8*)(w0 + 32768 + j * 512), A2);
  }
  #pragma unroll
  for (int j = 0; j < 8; j++) { ua[2*j] = ldc8(aRow + 512 + j * 32); ua[2*j+1] = ldc8(aRow + 512 + j * 32 + 4); }
  #pragma unroll
  for (int j = 0; j < 8; j++) {
    f16x8 av = toH(ub[2*j], ub[2*j+1]);
    int kt = 8 + j;
    A0 = MFMA_F16(av, *(const f16x8*)(w0 + kt * 512), A0);
    A1 = MFMA_F16(av, *(const f16x8*)(w0 + 16384 + kt * 512), A1);
    A2 = MFMA_F16(av, *(const f16x8*)(w0 + 32768 + kt * 512), A2);
  }
  #pragma unroll
  for (int j = 0; j < 8; j++) { ub[2*j] = ldc8(aRow + 768 + j * 32); ub[2*j+1] = ldc8(aRow + 768 + j * 32 + 4); }
  #pragma unroll
  for (int j = 0; j < 8; j++) {
    f16x8 av = toH(ua[2*j], ua[2*j+1]);
    int kt = 16 + j;
    A0 = MFMA_F16(av, *(const f16x8*)(w0 + kt * 512), A0);
    A1 = MFMA_F16(av, *(const f16x8*)(w0 + 16384 + kt * 512), A1);
    A2 = MFMA_F16(av, *(const f16x8*)(w0 + 32768 + kt * 512), A2);
  }
  #pragma unroll
  for (int j = 0; j < 8; j++) {
    f16x8 av = toH(ub[2*j], ub[2*j+1]);
    int kt = 24 + j;
    A0 = MFMA_F16(av, *(const f16x8*)(w0 + kt * 512), A0);
    A1 = MFMA_F16(av, *(const f16x8*)(w0 + 16384 + kt * 512), A1);
    A2 = MFMA_F16(av, *(const f16x8*)(w0 + 32768 + kt * 512), A2);
  }
}

__global__ __launch_bounds__(256, 1) void k_scan(Ptrs p) {
  extern __shared__ char smem[];
  f16* L = (f16*)smem;
  const int b = blockIdx.x, tid = threadIdx.x;
  const int w = tid >> 6, l = tid & 63;
  const int lm = l & 15, lq = l >> 4;

  // ---- one-time: stage weights into LDS (resident), preload biases ----
  {
    auto cp = [&](int dstF16, const f16* src, int nF16) {
      uint4* d = (uint4*)smem + (dstF16 >> 3);
      const uint4* s = (const uint4*)src;
      for (int i = tid; i < (nF16 >> 3); i += 256) d[i] = s[i];
    };
    if (b < 64) {
      cp(0,     p.wih0aP + (size_t)b * 16384, 16384);
      cp(16384, p.wih0aP + (size_t)(64 + b) * 16384, 16384);
      cp(32768, p.wih0aP + (size_t)(128 + b) * 16384, 16384);
      cp(49152, p.wih0bP + (size_t)b * 6144, 6144);
      cp(55296, p.wih0bP + (size_t)(64 + b) * 6144, 6144);
      cp(61440, p.wih0bP + (size_t)(128 + b) * 6144, 6144);
    } else if (b < 128) {
      int cb = b - 64;
      cp(0,     p.wih1P + (size_t)cb * 16384, 16384);
      cp(16384, p.wih1P + (size_t)(64 + cb) * 16384, 16384);
      cp(32768, p.wih1P + (size_t)(128 + cb) * 16384, 16384);
      cp(49152, p.embWP + (size_t)cb * 6144, 6144);
      if (cb < 8) cp(55296, p.predWP + (size_t)cb * 16384, 16384);
    } else if (b < 192) {
      int i = b - 128;
      cp(0,     p.whh0P + (size_t)i * 16384, 16384);
      cp(16384, p.whh0P + (size_t)(64 + i) * 16384, 16384);
      cp(32768, p.whh0P + (size_t)(128 + i) * 16384, 16384);
    } else {
      int i = b - 192;
      cp(0,     p.whh1P + (size_t)i * 16384, 16384);
      cp(16384, p.whh1P + (size_t)(64 + i) * 16384, 16384);
      cp(32768, p.whh1P + (size_t)(128 + i) * 16384, 16384);
    }
  }
  // per-lane constant biases + persistent GRU state (h0 or h1 slice in regs)
  float b0r = 0.f, b1r = 0.f, b2r = 0.f, ebr = 0.f, pbr = 0.f;
  float GsR = 0.f, BsR = 0.f;
  float hs[4] = {0.f, 0.f, 0.f, 0.f};
  if (b < 64) {
    int col = b * 16 + lm;
    b0r = p.bih0[col]; b1r = p.bih0[1024 + col]; b2r = p.bih0[2048 + col];
    #pragma unroll
    for (int r = 0; r < 4; r++) hs[r] = p.h0F[(size_t)(w * 16 + lq * 4 + r) * 1024 + col];
  } else if (b < 128) {
    int col = (b - 64) * 16 + lm;
    b0r = p.bih1[col]; b1r = p.bih1[1024 + col]; b2r = p.bih1[2048 + col];
    ebr = p.embB[col];
    #pragma unroll
    for (int r = 0; r < 4; r++) hs[r] = p.h1F[(size_t)(w * 16 + lq * 4 + r) * 1024 + col];
    if (b < 72 && col < 126) {
      pbr = p.predB[col];
      GsR = p.gsbs[col];
      BsR = p.gsbs[128 + col];
    }
  } else if (b < 192) {
    int col = (b - 128) * 16 + lm;
    b0r = p.bhh0[col]; b1r = p.bhh0[1024 + col]; b2r = p.bhh0[2048 + col];
  } else {
    int col = (b - 192) * 16 + lm;
    b0r = p.bhh1[col]; b1r = p.bhh1[1024 + col]; b2r = p.bhh1[2048 + col];
  }
  __syncthreads();

  unsigned* bar = p.bar;

  for (unsigned t = 0; t < TSTEPS; t++) {
    const f16* xc = p.xcat + (size_t)t * 24576;

    if (b < 64) {
      // ================= BB: gip (static + dyn) then h0n =================
      f32x4 a0 = {0,0,0,0}, a1 = {0,0,0,0}, a2 = {0,0,0,0};
      const f16* aB = xc + (w * 16 + lm) * 384 + lq * 8;
      const f16* wl = L + 49152 + l * 8;
      #pragma unroll
      for (int kt = 4; kt < 12; kt++) {
        f16x8 av = *(const f16x8*)(aB + kt * 32);
        a0 = MFMA_F16(av, *(const f16x8*)(wl + kt * 512), a0);
        a1 = MFMA_F16(av, *(const f16x8*)(wl + 6144 + kt * 512), a1);
        a2 = MFMA_F16(av, *(const f16x8*)(wl + 12288 + kt * 512), a2);
      }
      if (t) waitc(bar, S4, t, 8);
      f32x4 gip0, gip1, gip2;
      {
        u64 up[8];
        #pragma unroll
        for (int kt = 0; kt < 4; kt++) { up[2*kt] = ldc8(aB + kt * 32); up[2*kt+1] = ldc8(aB + kt * 32 + 4); }
        #pragma unroll
        for (int kt = 0; kt < 4; kt++) {
          f16x8 av = toH(up[2*kt], up[2*kt+1]);
          a0 = MFMA_F16(av, *(const f16x8*)(wl + kt * 512), a0);
          a1 = MFMA_F16(av, *(const f16x8*)(wl + 6144 + kt * 512), a1);
          a2 = MFMA_F16(av, *(const f16x8*)(wl + 12288 + kt * 512), a2);
        }
        #pragma unroll
        for (int r = 0; r < 4; r++) {
          gip0[r] = a0[r] + b0r; gip1[r] = a1[r] + b1r; gip2[r] = a2[r] + b2r;
        }
      }
      // gh0(t) produced off-path by GH0 last step: confirm flag, issue record loads
      waitc(bar, S3B, t, 64);
      const float* rec = p.ghP0 + ((size_t)((b * 16 + lm) * 16 + w * 4 + lq)) * 16;
      u64 r0 = ldc8(rec), r1 = ldc8(rec + 2), r2 = ldc8(rec + 4);
      u64 r3 = ldc8(rec + 6), r4 = ldc8(rec + 8), r5 = ldc8(rec + 10);
      waitc(bar, S1, t + 1, 64);
      {
        f32x4 A0 = {0,0,0,0}, A1 = {0,0,0,0}, A2 = {0,0,0,0};
        gemm3(p.ineB + (w * 16 + lm) * 1024 + lq * 8, L, l, A0, A1, A2);
        f32x4 g0 = toF(r0, r1), g1 = toF(r2, r3), g2 = toF(r4, r5);
        int col = b * 16 + lm;
        #pragma unroll
        for (int r = 0; r < 4; r++) {
          int row = w * 16 + lq * 4 + r;
          float r_ = sigmf(A0[r] + gip0[r] + g0[r]);
          float z_ = sigmf(A1[r] + gip1[r] + g1[r]);
          float n_ = tanhf_fast(A2[r] + gip2[r] + r_ * g2[r]);
          float hn = (1.f - z_) * n_ + z_ * hs[r];
          hs[r] = hn;
          st_pair(p.h0B + (size_t)row * 1024 + col, hn, lm, true);
        }
      }
      sigc(bar, S2, b, t + 1);
    } else if (b < 128) {
      // ================= CB: ine then h1n; cb<8 also pred =================
      int cb = b - 64;
      int col = cb * 16 + lm;
      // static ine k-tiles before S4 wait
      f32x4 acc = {0,0,0,0};
      const f16* aB = xc + (w * 16 + lm) * 384 + lq * 8;
      const f16* wl = L + 49152 + l * 8;
      #pragma unroll
      for (int kt = 4; kt < 12; kt++)
        acc = MFMA_F16(*(const f16x8*)(aB + kt * 32), *(const f16x8*)(wl + kt * 512), acc);
      if (t) waitc(bar, S4, t, 8);
      {
        u64 up[8];
        #pragma unroll
        for (int kt = 0; kt < 4; kt++) { up[2*kt] = ldc8(aB + kt * 32); up[2*kt+1] = ldc8(aB + kt * 32 + 4); }
        #pragma unroll
        for (int kt = 0; kt < 4; kt++)
          acc = MFMA_F16(toH(up[2*kt], up[2*kt+1]), *(const f16x8*)(wl + kt * 512), acc);
        #pragma unroll
        for (int r = 0; r < 4; r++) {
          int row = w * 16 + lq * 4 + r;
          float v = geluf(acc[r] + ebr);
          st_pair(p.ineB + (size_t)row * 1024 + col, v, lm, true);
        }
      }
      sigc(bar, S1, cb, t + 1);
      // gh1(t) off-path: confirm flag, issue record loads, then wait h0 (S2)
      waitc(bar, S4G, t, 64);
      const float* rec = p.ghP1 + ((size_t)((cb * 16 + lm) * 16 + w * 4 + lq)) * 16;
      u64 r0 = ldc8(rec), r1 = ldc8(rec + 2), r2 = ldc8(rec + 4);
      u64 r3 = ldc8(rec + 6), r4 = ldc8(rec + 8), r5 = ldc8(rec + 10);
      waitc(bar, S2, t + 1, 64);
      {
        f32x4 A0 = {0,0,0,0}, A1 = {0,0,0,0}, A2 = {0,0,0,0};
        gemm3(p.h0B + (w * 16 + lm) * 1024 + lq * 8, L, l, A0, A1, A2);
        f32x4 g0 = toF(r0, r1), g1 = toF(r2, r3), g2 = toF(r4, r5);
        #pragma unroll
        for (int r = 0; r < 4; r++) {
          int row = w * 16 + lq * 4 + r;
          float r_ = sigmf(A0[r] + b0r + g0[r]);
          float z_ = sigmf(A1[r] + b1r + g1[r]);
          float n_ = tanhf_fast(A2[r] + b2r + r_ * g2[r]);
          float hn = (1.f - z_) * n_ + z_ * hs[r];
          hs[r] = hn;
          st_pair(p.h1B + (size_t)row * 1024 + col, hn, lm, true);
        }
      }
      sigc(bar, S3, cb, t + 1);
      if (cb < 8) {
        // ---- pred: factored LayerNorm. GEMM uses raw h1B (ln_g folded into
        // predW'); LN stats computed IN-GEMM from the same loaded registers.
        // predsT stores deferred past the S4 signal (off critical drain) ----
        waitc(bar, S3, t + 1, 64);
        int myrow = w * 16 + lm;
        f32x4 pacc = {0,0,0,0};
        const f16* hB = p.h1B + (size_t)myrow * 1024 + lq * 8;
        const f16* wp = L + 55296 + l * 8;
        u64 ua[16], ub[16];
        float ssum = 0.f, ssq = 0.f;
        #pragma unroll
        for (int j = 0; j < 8; j++) { ua[2*j] = ldc8(hB + j * 32); ua[2*j+1] = ldc8(hB + j * 32 + 4); }
        #pragma unroll
        for (int j = 0; j < 8; j++) { ub[2*j] = ldc8(hB + 256 + j * 32); ub[2*j+1] = ldc8(hB + 256 + j * 32 + 4); }
        auto compP = [&](u64* cur, int g) {
          #pragma unroll
          for (int j = 0; j < 8; j++) {
            int kt = g * 8 + j;
            f16x8 hv = toH(cur[2*j], cur[2*j+1]);
            pacc = MFMA_F16(hv, *(const f16x8*)(wp + kt * 512), pacc);
            #pragma unroll
            for (int e = 0; e < 8; e++) {
              float v = (float)hv[e];
              ssum += v; ssq += v * v;
            }
          }
        };
        compP(ua, 0);
        #pragma unroll
        for (int j = 0; j < 8; j++) { ua[2*j] = ldc8(hB + 512 + j * 32); ua[2*j+1] = ldc8(hB + 512 + j * 32 + 4); }
        compP(ub, 1);
        #pragma unroll
        for (int j = 0; j < 8; j++) { ub[2*j] = ldc8(hB + 768 + j * 32); ub[2*j+1] = ldc8(hB + 768 + j * 32 + 4); }
        compP(ua, 2);
        compP(ub, 3);
        // stats for row myrow: reduce over the lq-group (lanes lm, lm+16, lm+32, lm+48)
        ssum += __shfl_xor(ssum, 16); ssq += __shfl_xor(ssq, 16);
        ssum += __shfl_xor(ssum, 32); ssq += __shfl_xor(ssq, 32);
        float outv[4];
        #pragma unroll
        for (int r = 0; r < 4; r++) {
          int row = w * 16 + lq * 4 + r;
          int src = (l & 48) | (lq * 4 + r);   // lane (same lq group) holding row's stats
          float ms = __shfl(ssum, src);
          float qs = __shfl(ssq, src);
          float mean = ms * 0.0009765625f;
          float var  = qs * 0.0009765625f - mean * mean;
          float rstd = rsqrtf(var + 1e-5f);
          float v = rstd * (pacc[r] - mean * GsR) + BsR + pbr;
          outv[r] = v;
          st_pair(p.xcat + (size_t)(t + 1) * 24576 + row * 384 + col, v, lm,
                  col < 126 && t < 447);
        }
        if (t == 447 && col < 126) {   // final step: predsT must drain before S4
          #pragma unroll
          for (int r = 0; r < 4; r++)
            stcf(&p.predsT[(size_t)t * 8064 + (w * 16 + lq * 4 + r) * 126 + col], outv[r]);
        }
        sigc(bar, S4, cb, t + 1);
        if (t < 447 && col < 126) {    // off-path: drained by next iteration's S1 sigc
          #pragma unroll
          for (int r = 0; r < 4; r++)
            stcf(&p.predsT[(size_t)t * 8064 + (w * 16 + lq * 4 + r) * 126 + col], outv[r]);
        }
      }
    } else if (b < 192) {
      // ================= GH0: gh0(t+1) =================
      int i = b - 128;
      waitc(bar, S2, t + 1, 64);
      {
        f32x4 A0 = {0,0,0,0}, A1 = {0,0,0,0}, A2 = {0,0,0,0};
        gemm3(p.h0B + (w * 16 + lm) * 1024 + lq * 8, L, l, A0, A1, A2);
        float* rec = p.ghP0 + ((size_t)((i * 16 + lm) * 16 + w * 4 + lq)) * 16;
        stc8(rec,      packF2(A0[0] + b0r, A0[1] + b0r));
        stc8(rec + 2,  packF2(A0[2] + b0r, A0[3] + b0r));
        stc8(rec + 4,  packF2(A1[0] + b1r, A1[1] + b1r));
        stc8(rec + 6,  packF2(A1[2] + b1r, A1[3] + b1r));
        stc8(rec + 8,  packF2(A2[0] + b2r, A2[1] + b2r));
        stc8(rec + 10, packF2(A2[2] + b2r, A2[3] + b2r));
      }
      sigc(bar, S3B, i, t + 1);
    } else {
      // ================= GH1: gh1(t+1) =================
      int i = b - 192;
      waitc(bar, S3, t + 1, 64);
      {
        f32x4 A0 = {0,0,0,0}, A1 = {0,0,0,0}, A2 = {0,0,0,0};
        gemm3(p.h1B + (w * 16 + lm) * 1024 + lq * 8, L, l, A0, A1, A2);
        float* rec = p.ghP1 + ((size_t)((i * 16 + lm) * 16 + w * 4 + lq)) * 16;
        stc8(rec,      packF2(A0[0] + b0r, A0[1] + b0r));
        stc8(rec + 2,  packF2(A0[2] + b0r, A0[3] + b0r));
        stc8(rec + 4,  packF2(A1[0] + b1r, A1[1] + b1r));
        stc8(rec + 6,  packF2(A1[2] + b1r, A1[3] + b1r));
        stc8(rec + 8,  packF2(A2[0] + b2r, A2[1] + b2r));
        stc8(rec + 10, packF2(A2[2] + b2r, A2[3] + b2r));
      }
      sigc(bar, S4G, i, t + 1);
    }
  }

  // ======== epilogue: predsT (t,n,m) -> out (n,m,t) ========
  waitc(bar, S4, TSTEPS, 8);
  {
    float* trS = (float*)smem;
    for (int g = b; g < 504; g += 256) {
      int p0 = g * 16;
      for (int t0 = 0; t0 < 448; t0 += 16) {
        int tc = tid >> 4, pp = tid & 15;
        trS[tc * 17 + pp] = p.predsT[(size_t)(t0 + tc) * 8064 + p0 + pp];
        __syncthreads();
        p.out[(size_t)(p0 + (tid >> 4)) * 448 + t0 + (tid & 15)] = trS[(tid & 15) * 17 + (tid >> 4)];
        __syncthreads();
      }
    }
  }
}

// ---------------- host ----------------

extern "C" void kernel_launch(void* const* d_in, const int* in_sizes, int n_in,
                              void* d_out, int out_size, void* d_ws, size_t ws_size,
                              hipStream_t stream) {
  Ptrs p;
  p.aud = (const float*)d_in[0];
  p.mo  = (const float*)d_in[1];
  p.lxm = (const float*)d_in[2];
  p.vid = (const int*)d_in[3];
  p.eps = (const float*)d_in[4];
  p.csi_w0 = (const float*)d_in[5];  p.csi_b0 = (const float*)d_in[6];
  p.csi_w1 = (const float*)d_in[7];  p.csi_b1 = (const float*)d_in[8];
  p.csi_w2 = (const float*)d_in[9];  p.csi_b2 = (const float*)d_in[10];
  p.spk  = (const float*)d_in[11];
  p.mu_w = (const float*)d_in[12];   p.mu_b = (const float*)d_in[13];
  p.lv_w = (const float*)d_in[14];   p.lv_b = (const float*)d_in[15];
  p.embW = (const float*)d_in[16];   p.embB = (const float*)d_in[17];
  p.wih0 = (const float*)d_in[18];   p.whh0 = (const float*)d_in[19];
  p.bih0 = (const float*)d_in[20];   p.bhh0 = (const float*)d_in[21];
  p.wih1 = (const float*)d_in[22];   p.whh1 = (const float*)d_in[23];
  p.bih1 = (const float*)d_in[24];   p.bhh1 = (const float*)d_in[25];
  p.ln_g = (const float*)d_in[26];   p.ln_b = (const float*)d_in[27];
  p.predW = (const float*)d_in[28];  p.predB = (const float*)d_in[29];
  p.out = (float*)d_out;

  char* ws = (char*)d_ws;
  size_t off = 0;
  auto al = [&](size_t bytes) -> void* {
    void* r = (void*)(ws + off);
    off += (bytes + 255) & ~(size_t)255;
    return r;
  };
  p.bar    = (unsigned*)al(65536);
  p.mu5    = (float*)al(640);
  p.lv5    = (float*)al(640);
  p.gsbs   = (float*)al(1024);
  p.h0F    = (float*)al(262144);
  p.h1F    = (float*)al(262144);
  p.h0B    = (f16*)al(131072);
  p.h1B    = (f16*)al(131072);
  p.ineB   = (f16*)al(131072);
  p.ghP0   = (float*)al(1048576);
  p.ghP1   = (float*)al(1048576);
  p.x0     = (float*)al(262144);
  p.x1     = (float*)al(262144);
  p.predsT = (float*)al(14450688);
  p.xcat   = (f16*)al(22020096);
  p.whh0P  = (f16*)al(6291456);
  p.whh1P  = (f16*)al(6291456);
  p.wih0aP = (f16*)al(6291456);
  p.wih0bP = (f16*)al(2359296);
  p.wih1P  = (f16*)al(6291456);
  p.embWP  = (f16*)al(786432);
  p.predWP = (f16*)al(262144);

  k_init<<<64, 256, 0, stream>>>(p);

  k_pack<<<dim3(192, 32), 256, 0, stream>>>(p.whh0, p.whh0P, 1024, 0, 3072, 3072, nullptr);
  k_pack<<<dim3(192, 32), 256, 0, stream>>>(p.whh1, p.whh1P, 1024, 0, 3072, 3072, nullptr);
  k_pack<<<dim3(192, 32), 256, 0, stream>>>(p.wih0, p.wih0aP, 1024, 0, 3072, 3072, nullptr);
  k_pack<<<dim3(192, 12), 256, 0, stream>>>(p.wih0, p.wih0bP, 382, 1024, 3072, 3072, nullptr);
  k_pack<<<dim3(192, 32), 256, 0, stream>>>(p.wih1, p.wih1P, 1024, 0, 3072, 3072, nullptr);
  k_pack<<<dim3(64, 12), 256, 0, stream>>>(p.embW, p.embWP, 382, 0, 1024, 1024, nullptr);
  // predW packed with ln_g folded in (factored LayerNorm)
  k_pack<<<dim3(8, 32), 256, 0, stream>>>(p.predW, p.predWP, 1024, 0, 126, 126, p.ln_g);

  k_gsbs<<<1, 128, 0, stream>>>(p);
  k_csi1<<<256, 256, 0, stream>>>(p);
  k_csi2<<<256, 256, 0, stream>>>(p);
  k_csi3<<<512, 256, 0, stream>>>(p);
  k_gh<<<1536, 256, 0, stream>>>(p);
  k_style1<<<1, 256, 0, stream>>>(p);
  k_style2<<<3584, 256, 0, stream>>>(p);
  k_aud<<<1792, 256, 0, stream>>>(p);
  k_lxm<<<10752, 256, 0, stream>>>(p);
  k_premo0<<<32, 256, 0, stream>>>(p);
  k_padz<<<224, 256, 0, stream>>>(p);

  k_scan<<<256, 256, LDS_BYTES, stream>>>(p);

  (void)in_sizes; (void)n_in; (void)out_size; (void)ws_size;
}

// Round 12
// 14302.617 us; speedup vs baseline: 1.2390x; 1.0032x over previous
//
#include <hip/hip_runtime.h>
#include <cmath>

typedef _Float16 f16;
typedef _Float16 f16x8 __attribute__((ext_vector_type(8)));
typedef float f32x4 __attribute__((ext_vector_type(4)));
typedef unsigned long long u64;

#define MFMA_F16(a,b,c) __builtin_amdgcn_mfma_f32_16x16x32_f16((a),(b),(c),0,0,0)
#define AGENT __HIP_MEMORY_SCOPE_AGENT

// N=64, A=128, MO=126, LX=96, H=1024, S=32, P=2, B=16, BL=32, T=448
#define TSTEPS 448
#define OFF_MU 3612672   // 64*126*448
#define OFF_LV 4530176   // + 64*32*448
#define LDS_BYTES 156160

// signal classes (per-block flags: flag(cls, idx) = bar[(cls*64+idx)*32])
#define S1 0   // ineB ready        (64 signalers, idx b-64)
#define S2 1   // h0B ready         (64, idx b)
#define S3 2   // h1B ready         (64, idx b-64)
#define S3B 3  // gh0(t+1) ready    (64, idx b-128)
#define S4 4   // xcat(t+1)/pred    (8, idx b-64)
#define S4G 5  // gh1(t+1) ready    (64, idx b-192)

struct Ptrs {
  const float *aud, *mo, *lxm, *eps;
  const int *vid;
  const float *csi_w0, *csi_b0, *csi_w1, *csi_b1, *csi_w2, *csi_b2;
  const float *spk, *mu_w, *mu_b, *lv_w, *lv_b;
  const float *embW, *embB;
  const float *wih0, *whh0, *bih0, *bhh0;
  const float *wih1, *whh1, *bih1, *bhh1;
  const float *ln_g, *ln_b, *predW, *predB;
  float *out;
  unsigned *bar;
  float *mu5, *lv5, *h0F, *h1F, *gsbs;
  f16 *h0B, *h1B, *ineB, *xcat;
  float *ghP0, *ghP1, *x0, *x1, *predsT;
  f16 *whh0P, *whh1P, *wih0aP, *wih0bP, *wih1P, *embWP, *predWP;
};

__device__ __forceinline__ float geluf(float x) {
  return 0.5f * x * (1.0f + erff(x * 0.7071067811865475f));
}
// fast sigmoid/tanh: __expf + v_rcp (abs err ~1e-6, tolerance is 1.5e-2)
__device__ __forceinline__ float sigmf(float x) {
  return __builtin_amdgcn_rcpf(1.0f + __expf(-x));
}
__device__ __forceinline__ float tanhf_fast(float x) {
  float xc = fmaxf(x, -44.f);           // avoid exp overflow -> -inf*0 NaN
  float e = __expf(-2.f * xc);
  return (1.f - e) * __builtin_amdgcn_rcpf(1.f + e);
}

// ---- coherent (cross-XCD) primitives: compiler-visible, batchable ----
__device__ __forceinline__ u64 ldc8(const void* p) {
  return __hip_atomic_load((const u64*)p, __ATOMIC_RELAXED, AGENT);
}
__device__ __forceinline__ void stc8(void* p, u64 v) {
  __hip_atomic_store((u64*)p, v, __ATOMIC_RELAXED, AGENT);
}
__device__ __forceinline__ void stcf(float* p, float v) {
  __hip_atomic_store(p, v, __ATOMIC_RELAXED, AGENT);
}
__device__ __forceinline__ f16x8 toH(u64 a, u64 b) {
  union { u64 u[2]; f16x8 h; } r; r.u[0] = a; r.u[1] = b; return r.h;
}
__device__ __forceinline__ f32x4 toF(u64 a, u64 b) {
  union { u64 u[2]; f32x4 f; } r; r.u[0] = a; r.u[1] = b; return r.f;
}
__device__ __forceinline__ u64 packF2(float a, float b) {
  union { float f[2]; u64 u; } r; r.f[0] = a; r.f[1] = b; return r.u;
}
// pack (v, lane^1's v) into 2 f16 and store 4B coherently from even lanes
__device__ __forceinline__ void st_pair(f16* base, float v, int lm, bool pred) {
  float vn = __shfl_xor(v, 1);
  if (!(lm & 1) && pred) {
    union { f16 h[2]; unsigned u; } pk;
    pk.h[0] = (f16)v; pk.h[1] = (f16)vn;
    __hip_atomic_store((unsigned*)base, pk.u, __ATOMIC_RELAXED, AGENT);
  }
}

// ---------------- prologue kernels ----------------

__global__ void k_init(Ptrs p) {
  int gid = blockIdx.x * 256 + threadIdx.x;
  if (gid < 16384) p.bar[gid] = 0u;
}

__global__ void k_pack(const float* __restrict__ src, f16* __restrict__ dst,
                       int K, int rowOff, int realN, int ldN,
                       const float* __restrict__ scale) {
  int ct = blockIdx.x, kt = blockIdx.y;
  int e = threadIdx.x * 2;
  int l = e >> 3, i = e & 7;
  int k = kt * 32 + (l >> 4) * 8 + i;
  int col = ct * 16 + (l & 15);
  f16 v0 = (f16)0.f, v1 = (f16)0.f;
  if (k < K && col < realN) {
    float s = scale ? scale[rowOff + k] : 1.f;
    v0 = (f16)(src[(size_t)(rowOff + k) * ldN + col] * s);
  }
  if (k + 1 < K && col < realN) {
    float s = scale ? scale[rowOff + k + 1] : 1.f;
    v1 = (f16)(src[(size_t)(rowOff + k + 1) * ldN + col] * s);
  }
  size_t o = ((size_t)ct * gridDim.y + kt) * 512 + e;
  dst[o] = v0; dst[o + 1] = v1;
}

// Gs[m] = sum_k ln_g[k]*predW[k,m]; Bs[m] = sum_k ln_b[k]*predW[k,m]
__global__ void k_gsbs(Ptrs p) {
  int c = threadIdx.x;
  if (c < 126) {
    float gs = 0.f, bs = 0.f;
    for (int k = 0; k < 1024; k++) {
      float w = p.predW[(size_t)k * 126 + c];
      gs += p.ln_g[k] * w;
      bs += p.ln_b[k] * w;
    }
    p.gsbs[c] = gs; p.gsbs[128 + c] = bs;
  }
}

__global__ void k_csi1(Ptrs p) {
  int gid = blockIdx.x * 256 + threadIdx.x;  // 65536
  int n = gid >> 10, c = gid & 1023;
  float acc = p.csi_b0[c];
  const float* w = p.csi_w0 + c;
  for (int k = 0; k < 126; k++) acc += p.mo[((size_t)(n * 126 + k)) * 512 + 31] * w[(size_t)k * 1024];
  for (int k = 0; k < 96; k++)  acc += p.lxm[(size_t)(n * 96 + k) * 16] * w[(size_t)(126 + k) * 1024];
  p.x0[gid] = geluf(acc);
}

__global__ void k_csi2(Ptrs p) {
  int gid = blockIdx.x * 256 + threadIdx.x;
  int n = gid >> 10, c = gid & 1023;
  float acc = p.csi_b1[c];
  const float* w = p.csi_w1 + c;
  const float* x = p.x0 + (size_t)n * 1024;
  for (int k = 0; k < 1024; k++) acc += x[k] * w[(size_t)k * 1024];
  p.x1[gid] = geluf(acc);
}

__global__ void k_csi3(Ptrs p) {
  int gid = blockIdx.x * 256 + threadIdx.x;
  int n = gid >> 11, c2 = gid & 2047;
  float acc = p.csi_b2[c2];
  const float* w = p.csi_w2 + c2;
  const float* x = p.x1 + (size_t)n * 1024;
  for (int k = 0; k < 1024; k++) acc += x[k] * w[(size_t)k * 2048];
  if (c2 < 1024) { p.h0F[n * 1024 + c2] = acc; p.h0B[n * 1024 + c2] = (f16)acc; }
  else           { p.h1F[n * 1024 + c2 - 1024] = acc; p.h1B[n * 1024 + c2 - 1024] = (f16)acc; }
}

// initial gh0/gh1 for t=0, packed per-consumer-lane records:
// ghP[((ct*16+lm)*16 + w*4+lq)*16 + g*4 + r], row = w*16+lq*4+r, col = g*1024 + ct*16+lm
__global__ void k_gh(Ptrs p) {
  int gid = blockIdx.x * 256 + threadIdx.x;  // 393216
  int which = gid >= 196608;
  int g2 = which ? gid - 196608 : gid;
  int n = g2 / 3072, c = g2 % 3072;
  const float* h = which ? p.h1F : p.h0F;
  const float* W = which ? p.whh1 : p.whh0;
  const float* bb = which ? p.bhh1 : p.bhh0;
  float acc = bb[c];
  const float* hr = h + (size_t)n * 1024;
  for (int k = 0; k < 1024; k++) acc += hr[k] * W[(size_t)k * 3072 + c];
  int g = c >> 10, col = c & 1023;
  int ct = col >> 4, lm = col & 15, w = n >> 4, lq = (n >> 2) & 3, r = n & 3;
  float* dst = which ? p.ghP1 : p.ghP0;
  dst[((size_t)((ct * 16 + lm) * 16 + w * 4 + lq)) * 16 + g * 4 + r] = acc;
}

__global__ void k_style1(Ptrs p) {
  int tid = threadIdx.x;
  if (tid < 160) {
    int v = tid >> 5, s = tid & 31;
    float m = p.mu_b[s], lv = p.lv_b[s];
    for (int k = 0; k < 32; k++) {
      float z = p.spk[v * 32 + k];
      m += z * p.mu_w[k * 32 + s];
      lv += z * p.lv_w[k * 32 + s];
    }
    p.mu5[v * 32 + s] = m; p.lv5[v * 32 + s] = lv;
  }
}

__global__ void k_style2(Ptrs p) {
  int gid = blockIdx.x * 256 + threadIdx.x;  // 917504
  int t = gid % 448;
  int rr = gid / 448;
  int s = rr & 31, n = rr >> 5;
  int v = p.vid[n * 16 + (t >> 5) + 1];
  float mu = p.mu5[v * 32 + s], lv = p.lv5[v * 32 + s];
  float e = p.eps[((size_t)t * 64 + n) * 32 + s];
  float st = mu + e * expf(0.5f * lv);
  p.out[OFF_MU + ((size_t)n * 32 + s) * 448 + t] = mu;
  p.out[OFF_LV + ((size_t)n * 32 + s) * 448 + t] = lv;
  p.xcat[((size_t)t * 64 + n) * 384 + 350 + s] = (f16)st;
}

__global__ void k_aud(Ptrs p) {
  __shared__ float tile[32][65];
  int bid = blockIdx.x;  // 64*4*7
  int n = bid / 28, rem = bid % 28;
  int a0 = (rem / 7) * 32, t0 = (rem % 7) * 64;
  int tid = threadIdx.x;
  for (int i = tid; i < 2048; i += 256) {
    int ai = i >> 6, tj = i & 63;
    tile[ai][tj] = p.aud[((size_t)n * 128 + a0 + ai) * 448 + t0 + tj];
  }
  __syncthreads();
  for (int i = tid; i < 2048; i += 256) {
    int tj = i >> 5, ai = i & 31;
    p.xcat[((size_t)(t0 + tj) * 64 + n) * 384 + 126 + a0 + ai] = (f16)tile[ai][tj];
  }
}

__global__ void k_lxm(Ptrs p) {
  int gid = blockIdx.x * 256 + threadIdx.x;  // 2752512
  int l_ = gid % 96;
  int r = gid / 96;
  int n = r & 63, t = r >> 6;
  int tb = (t >> 5) + 1;
  p.xcat[((size_t)t * 64 + n) * 384 + 254 + l_] = (f16)p.lxm[((size_t)n * 96 + l_) * 16 + tb];
}

__global__ void k_premo0(Ptrs p) {
  int gid = blockIdx.x * 256 + threadIdx.x;
  if (gid < 8064) {
    int n = gid / 126, m = gid % 126;
    p.xcat[(size_t)n * 384 + m] = (f16)p.mo[((size_t)n * 126 + m) * 512 + 31];
  }
}

__global__ void k_padz(Ptrs p) {
  int gid = blockIdx.x * 256 + threadIdx.x;  // 57344
  int t = gid >> 7, rem = gid & 127;
  int n = rem >> 1, c = 382 + (rem & 1);
  p.xcat[((size_t)t * 64 + n) * 384 + c] = (f16)0.f;
}

// ---------------- persistent scan kernel ----------------

// signal: drain stores, then plain agent store of step value (one writer/flag)
__device__ __forceinline__ void sigc(unsigned* bar, int cls, int idx, unsigned val) {
  asm volatile("s_waitcnt vmcnt(0)" ::: "memory");
  __syncthreads();
  if (threadIdx.x == 0)
    __hip_atomic_store(&bar[(cls * 64 + idx) * 32], val, __ATOMIC_RELAXED, AGENT);
}
// busy-poll: nsig lanes each watch one producer's flag
__device__ __forceinline__ void waitc(unsigned* bar, int cls, unsigned tgt, int nsig) {
  if (threadIdx.x < (unsigned)nsig) {
    const unsigned* f = &bar[(cls * 64 + threadIdx.x) * 32];
    while (__hip_atomic_load(f, __ATOMIC_RELAXED, AGENT) < tgt) {}
  }
  __syncthreads();
}

// pipelined 3-gate GEMM: A row coherent (batched u64 loads, double-buffered),
// weights LDS-resident at L+{0,16384,32768} (f16 offsets)
__device__ __forceinline__ void gemm3(const f16* aRow, const f16* L, int l,
                                      f32x4& A0, f32x4& A1, f32x4& A2) {
  const f16* w0 = L + l * 8;
  u64 ua[16], ub[16];
  #pragma unroll
  for (int j = 0; j < 8; j++) { ua[2*j] = ldc8(aRow + j * 32); ua[2*j+1] = ldc8(aRow + j * 32 + 4); }
  #pragma unroll
  for (int j = 0; j < 8; j++) { ub[2*j] = ldc8(aRow + 256 + j * 32); ub[2*j+1] = ldc8(aRow + 256 + j * 32 + 4); }
  #pragma unroll
  for (int j = 0; j < 8; j++) {
    f16x8 av = toH(ua[2*j], ua[2*j+1]);
    A0 = MFMA_F16(av, *(const f16x8*)(w0 + j * 512), A0);
    A1 = MFMA_F16(av, *(const f16x8*)(w0 + 16384 + j * 512), A1);
    A2 = MFMA_F16(av, *(const f16x8*)(w0 + 32768 + j * 512), A2);
  }
  #pragma unroll
  for (int j = 0; j < 8; j++) { ua[2*j] = ldc8(aRow + 512 + j * 32); ua[2*j+1] = ldc8(aRow + 512 + j * 32 + 4); }
  #pragma unroll
  for (int j = 0; j < 8; j++) {
    f16x8 av = toH(ub[2*j], ub[2*j+1]);
    int kt = 8 + j;
    A0 = MFMA_F16(av, *(const f16x8*)(w0 + kt * 512), A0);
    A1 = MFMA_F16(av, *(const f16x8*)(w0 + 16384 + kt * 512), A1);
    A2 = MFMA_F16(av, *(const f16x8*)(w0 + 32768 + kt * 512), A2);
  }
  #pragma unroll
  for (int j = 0; j < 8; j++) { ub[2*j] = ldc8(aRow + 768 + j * 32); ub[2*j+1] = ldc8(aRow + 768 + j * 32 + 4); }
  #pragma unroll
  for (int j = 0; j < 8; j++) {
    f16x8 av = toH(ua[2*j], ua[2*j+1]);
    int kt = 16 + j;
    A0 = MFMA_F16(av, *(const f16x8*)(w0 + kt * 512), A0);
    A1 = MFMA_F16(av, *(const f16x8*)(w0 + 16384 + kt * 512), A1);
    A2 = MFMA_F16(av, *(const f16x8*)(w0 + 32768 + kt * 512), A2);
  }
  #pragma unroll
  for (int j = 0; j < 8; j++) {
    f16x8 av = toH(ub[2*j], ub[2*j+1]);
    int kt = 24 + j;
    A0 = MFMA_F16(av, *(const f16x8*)(w0 + kt * 512), A0);
    A1 = MFMA_F16(av, *(const f16x8*)(w0 + 16384 + kt * 512), A1);
    A2 = MFMA_F16(av, *(const f16x8*)(w0 + 32768 + kt * 512), A2);
  }
}

__global__ __launch_bounds__(256, 1) void k_scan(Ptrs p) {
  extern __shared__ char smem[];
  f16* L = (f16*)smem;
  const int b = blockIdx.x, tid = threadIdx.x;
  const int w = tid >> 6, l = tid & 63;
  const int lm = l & 15, lq = l >> 4;

  // ---- one-time: stage weights into LDS (resident), preload biases ----
  {
    auto cp = [&](int dstF16, const f16* src, int nF16) {
      uint4* d = (uint4*)smem + (dstF16 >> 3);
      const uint4* s = (const uint4*)src;
      for (int i = tid; i < (nF16 >> 3); i += 256) d[i] = s[i];
    };
    if (b < 64) {
      cp(0,     p.wih0aP + (size_t)b * 16384, 16384);
      cp(16384, p.wih0aP + (size_t)(64 + b) * 16384, 16384);
      cp(32768, p.wih0aP + (size_t)(128 + b) * 16384, 16384);
      cp(49152, p.wih0bP + (size_t)b * 6144, 6144);
      cp(55296, p.wih0bP + (size_t)(64 + b) * 6144, 6144);
      cp(61440, p.wih0bP + (size_t)(128 + b) * 6144, 6144);
    } else if (b < 128) {
      int cb = b - 64;
      cp(0,     p.wih1P + (size_t)cb * 16384, 16384);
      cp(16384, p.wih1P + (size_t)(64 + cb) * 16384, 16384);
      cp(32768, p.wih1P + (size_t)(128 + cb) * 16384, 16384);
      cp(49152, p.embWP + (size_t)cb * 6144, 6144);
      if (cb < 8) cp(55296, p.predWP + (size_t)cb * 16384, 16384);
    } else if (b < 192) {
      int i = b - 128;
      cp(0,     p.whh0P + (size_t)i * 16384, 16384);
      cp(16384, p.whh0P + (size_t)(64 + i) * 16384, 16384);
      cp(32768, p.whh0P + (size_t)(128 + i) * 16384, 16384);
    } else {
      int i = b - 192;
      cp(0,     p.whh1P + (size_t)i * 16384, 16384);
      cp(16384, p.whh1P + (size_t)(64 + i) * 16384, 16384);
      cp(32768, p.whh1P + (size_t)(128 + i) * 16384, 16384);
    }
  }
  // per-lane constant biases + persistent GRU state (h0 or h1 slice in regs)
  float b0r = 0.f, b1r = 0.f, b2r = 0.f, ebr = 0.f, pbr = 0.f;
  float GsR = 0.f, BsR = 0.f;
  float hs[4] = {0.f, 0.f, 0.f, 0.f};
  if (b < 64) {
    int col = b * 16 + lm;
    b0r = p.bih0[col]; b1r = p.bih0[1024 + col]; b2r = p.bih0[2048 + col];
    #pragma unroll
    for (int r = 0; r < 4; r++) hs[r] = p.h0F[(size_t)(w * 16 + lq * 4 + r) * 1024 + col];
  } else if (b < 128) {
    int col = (b - 64) * 16 + lm;
    b0r = p.bih1[col]; b1r = p.bih1[1024 + col]; b2r = p.bih1[2048 + col];
    ebr = p.embB[col];
    #pragma unroll
    for (int r = 0; r < 4; r++) hs[r] = p.h1F[(size_t)(w * 16 + lq * 4 + r) * 1024 + col];
    if (b < 72 && col < 126) {
      pbr = p.predB[col];
      GsR = p.gsbs[col];
      BsR = p.gsbs[128 + col];
    }
  } else if (b < 192) {
    int col = (b - 128) * 16 + lm;
    b0r = p.bhh0[col]; b1r = p.bhh0[1024 + col]; b2r = p.bhh0[2048 + col];
  } else {
    int col = (b - 192) * 16 + lm;
    b0r = p.bhh1[col]; b1r = p.bhh1[1024 + col]; b2r = p.bhh1[2048 + col];
  }
  __syncthreads();

  unsigned* bar = p.bar;

  for (unsigned t = 0; t < TSTEPS; t++) {
    const f16* xc = p.xcat + (size_t)t * 24576;

    if (b < 64) {
      // ================= BB: gip (static + dyn) then h0n =================
      f32x4 a0 = {0,0,0,0}, a1 = {0,0,0,0}, a2 = {0,0,0,0};
      const f16* aB = xc + (w * 16 + lm) * 384 + lq * 8;
      const f16* wl = L + 49152 + l * 8;
      #pragma unroll
      for (int kt = 4; kt < 12; kt++) {
        f16x8 av = *(const f16x8*)(aB + kt * 32);
        a0 = MFMA_F16(av, *(const f16x8*)(wl + kt * 512), a0);
        a1 = MFMA_F16(av, *(const f16x8*)(wl + 6144 + kt * 512), a1);
        a2 = MFMA_F16(av, *(const f16x8*)(wl + 12288 + kt * 512), a2);
      }
      if (t) waitc(bar, S4, t, 8);
      f32x4 gip0, gip1, gip2;
      {
        u64 up[8];
        #pragma unroll
        for (int kt = 0; kt < 4; kt++) { up[2*kt] = ldc8(aB + kt * 32); up[2*kt+1] = ldc8(aB + kt * 32 + 4); }
        #pragma unroll
        for (int kt = 0; kt < 4; kt++) {
          f16x8 av = toH(up[2*kt], up[2*kt+1]);
          a0 = MFMA_F16(av, *(const f16x8*)(wl + kt * 512), a0);
          a1 = MFMA_F16(av, *(const f16x8*)(wl + 6144 + kt * 512), a1);
          a2 = MFMA_F16(av, *(const f16x8*)(wl + 12288 + kt * 512), a2);
        }
        #pragma unroll
        for (int r = 0; r < 4; r++) {
          gip0[r] = a0[r] + b0r; gip1[r] = a1[r] + b1r; gip2[r] = a2[r] + b2r;
        }
      }
      // gh0(t) produced off-path by GH0 last step: confirm flag, issue record loads
      waitc(bar, S3B, t, 64);
      const float* rec = p.ghP0 + ((size_t)((b * 16 + lm) * 16 + w * 4 + lq)) * 16;
      u64 r0 = ldc8(rec), r1 = ldc8(rec + 2), r2 = ldc8(rec + 4);
      u64 r3 = ldc8(rec + 6), r4 = ldc8(rec + 8), r5 = ldc8(rec + 10);
      waitc(bar, S1, t + 1, 64);
      {
        f32x4 A0 = {0,0,0,0}, A1 = {0,0,0,0}, A2 = {0,0,0,0};
        gemm3(p.ineB + (w * 16 + lm) * 1024 + lq * 8, L, l, A0, A1, A2);
        f32x4 g0 = toF(r0, r1), g1 = toF(r2, r3), g2 = toF(r4, r5);
        int col = b * 16 + lm;
        #pragma unroll
        for (int r = 0; r < 4; r++) {
          int row = w * 16 + lq * 4 + r;
          float r_ = sigmf(A0[r] + gip0[r] + g0[r]);
          float z_ = sigmf(A1[r] + gip1[r] + g1[r]);
          float n_ = tanhf_fast(A2[r] + gip2[r] + r_ * g2[r]);
          float hn = (1.f - z_) * n_ + z_ * hs[r];
          hs[r] = hn;
          st_pair(p.h0B + (size_t)row * 1024 + col, hn, lm, true);
        }
      }
      sigc(bar, S2, b, t + 1);
    } else if (b < 128) {
      // ================= CB: ine then h1n; cb<8 also pred =================
      int cb = b - 64;
      int col = cb * 16 + lm;
      // static ine k-tiles before S4 wait
      f32x4 acc = {0,0,0,0};
      const f16* aB = xc + (w * 16 + lm) * 384 + lq * 8;
      const f16* wl = L + 49152 + l * 8;
      #pragma unroll
      for (int kt = 4; kt < 12; kt++)
        acc = MFMA_F16(*(const f16x8*)(aB + kt * 32), *(const f16x8*)(wl + kt * 512), acc);
      if (t) waitc(bar, S4, t, 8);
      {
        u64 up[8];
        #pragma unroll
        for (int kt = 0; kt < 4; kt++) { up[2*kt] = ldc8(aB + kt * 32); up[2*kt+1] = ldc8(aB + kt * 32 + 4); }
        #pragma unroll
        for (int kt = 0; kt < 4; kt++)
          acc = MFMA_F16(toH(up[2*kt], up[2*kt+1]), *(const f16x8*)(wl + kt * 512), acc);
        #pragma unroll
        for (int r = 0; r < 4; r++) {
          int row = w * 16 + lq * 4 + r;
          float v = geluf(acc[r] + ebr);
          st_pair(p.ineB + (size_t)row * 1024 + col, v, lm, true);
        }
      }
      sigc(bar, S1, cb, t + 1);
      // gh1(t) off-path: confirm flag, issue record loads, then wait h0 (S2)
      waitc(bar, S4G, t, 64);
      const float* rec = p.ghP1 + ((size_t)((cb * 16 + lm) * 16 + w * 4 + lq)) * 16;
      u64 r0 = ldc8(rec), r1 = ldc8(rec + 2), r2 = ldc8(rec + 4);
      u64 r3 = ldc8(rec + 6), r4 = ldc8(rec + 8), r5 = ldc8(rec + 10);
      waitc(bar, S2, t + 1, 64);
      {
        f32x4 A0 = {0,0,0,0}, A1 = {0,0,0,0}, A2 = {0,0,0,0};
        gemm3(p.h0B + (w * 16 + lm) * 1024 + lq * 8, L, l, A0, A1, A2);
        f32x4 g0 = toF(r0, r1), g1 = toF(r2, r3), g2 = toF(r4, r5);
        #pragma unroll
        for (int r = 0; r < 4; r++) {
          int row = w * 16 + lq * 4 + r;
          float r_ = sigmf(A0[r] + b0r + g0[r]);
          float z_ = sigmf(A1[r] + b1r + g1[r]);
          float n_ = tanhf_fast(A2[r] + b2r + r_ * g2[r]);
          float hn = (1.f - z_) * n_ + z_ * hs[r];
          hs[r] = hn;
          st_pair(p.h1B + (size_t)row * 1024 + col, hn, lm, true);
        }
      }
      sigc(bar, S3, cb, t + 1);
      if (cb < 8) {
        // ---- pred: factored LayerNorm. GEMM uses raw h1B (ln_g folded into
        // predW'); LN stats computed IN-GEMM from the same loaded registers.
        // predsT stores deferred past the S4 signal (off critical drain) ----
        waitc(bar, S3, t + 1, 64);
        int myrow = w * 16 + lm;
        f32x4 pacc = {0,0,0,0};
        const f16* hB = p.h1B + (size_t)myrow * 1024 + lq * 8;
        const f16* wp = L + 55296 + l * 8;
        u64 ua[16], ub[16];
        float ssum = 0.f, ssq = 0.f;
        #pragma unroll
        for (int j = 0; j < 8; j++) { ua[2*j] = ldc8(hB + j * 32); ua[2*j+1] = ldc8(hB + j * 32 + 4); }
        #pragma unroll
        for (int j = 0; j < 8; j++) { ub[2*j] = ldc8(hB + 256 + j * 32); ub[2*j+1] = ldc8(hB + 256 + j * 32 + 4); }
        auto compP = [&](u64* cur, int g) {
          #pragma unroll
          for (int j = 0; j < 8; j++) {
            int kt = g * 8 + j;
            f16x8 hv = toH(cur[2*j], cur[2*j+1]);
            pacc = MFMA_F16(hv, *(const f16x8*)(wp + kt * 512), pacc);
            #pragma unroll
            for (int e = 0; e < 8; e++) {
              float v = (float)hv[e];
              ssum += v; ssq += v * v;
            }
          }
        };
        compP(ua, 0);
        #pragma unroll
        for (int j = 0; j < 8; j++) { ua[2*j] = ldc8(hB + 512 + j * 32); ua[2*j+1] = ldc8(hB + 512 + j * 32 + 4); }
        compP(ub, 1);
        #pragma unroll
        for (int j = 0; j < 8; j++) { ub[2*j] = ldc8(hB + 768 + j * 32); ub[2*j+1] = ldc8(hB + 768 + j * 32 + 4); }
        compP(ua, 2);
        compP(ub, 3);
        // stats for row myrow: reduce over the lq-group (lanes lm, lm+16, lm+32, lm+48)
        ssum += __shfl_xor(ssum, 16); ssq += __shfl_xor(ssq, 16);
        ssum += __shfl_xor(ssum, 32); ssq += __shfl_xor(ssq, 32);
        float outv[4];
        #pragma unroll
        for (int r = 0; r < 4; r++) {
          int row = w * 16 + lq * 4 + r;
          int src = (l & 48) | (lq * 4 + r);   // lane (same lq group) holding row's stats
          float ms = __shfl(ssum, src);
          float qs = __shfl(ssq, src);
          float mean = ms * 0.0009765625f;
          float var  = qs * 0.0009765625f - mean * mean;
          float rstd = rsqrtf(var + 1e-5f);
          float v = rstd * (pacc[r] - mean * GsR) + BsR + pbr;
          outv[r] = v;
          st_pair(p.xcat + (size_t)(t + 1) * 24576 + row * 384 + col, v, lm,
                  col < 126 && t < 447);
        }
        if (t == 447 && col < 126) {   // final step: predsT must drain before S4
          #pragma unroll
          for (int r = 0; r < 4; r++)
            stcf(&p.predsT[(size_t)t * 8064 + (w * 16 + lq * 4 + r) * 126 + col], outv[r]);
        }
        sigc(bar, S4, cb, t + 1);
        if (t < 447 && col < 126) {    // off-path: drained by next iteration's S1 sigc
          #pragma unroll
          for (int r = 0; r < 4; r++)
            stcf(&p.predsT[(size_t)t * 8064 + (w * 16 + lq * 4 + r) * 126 + col], outv[r]);
        }
      }
    } else if (b < 192) {
      // ================= GH0: gh0(t+1) =================
      int i = b - 128;
      waitc(bar, S2, t + 1, 64);
      {
        f32x4 A0 = {0,0,0,0}, A1 = {0,0,0,0}, A2 = {0,0,0,0};
        gemm3(p.h0B + (w * 16 + lm) * 1024 + lq * 8, L, l, A0, A1, A2);
        float* rec = p.ghP0 + ((size_t)((i * 16 + lm) * 16 + w * 4 + lq)) * 16;
        stc8(rec,      packF2(A0[0] + b0r, A0[1] + b0r));
        stc8(rec + 2,  packF2(A0[2] + b0r, A0[3] + b0r));
        stc8(rec + 4,  packF2(A1[0] + b1r, A1[1] + b1r));
        stc8(rec + 6,  packF2(A1[2] + b1r, A1[3] + b1r));
        stc8(rec + 8,  packF2(A2[0] + b2r, A2[1] + b2r));
        stc8(rec + 10, packF2(A2[2] + b2r, A2[3] + b2r));
      }
      sigc(bar, S3B, i, t + 1);
    } else {
      // ================= GH1: gh1(t+1) =================
      int i = b - 192;
      waitc(bar, S3, t + 1, 64);
      {
        f32x4 A0 = {0,0,0,0}, A1 = {0,0,0,0}, A2 = {0,0,0,0};
        gemm3(p.h1B + (w * 16 + lm) * 1024 + lq * 8, L, l, A0, A1, A2);
        float* rec = p.ghP1 + ((size_t)((i * 16 + lm) * 16 + w * 4 + lq)) * 16;
        stc8(rec,      packF2(A0[0] + b0r, A0[1] + b0r));
        stc8(rec + 2,  packF2(A0[2] + b0r, A0[3] + b0r));
        stc8(rec + 4,  packF2(A1[0] + b1r, A1[1] + b1r));
        stc8(rec + 6,  packF2(A1[2] + b1r, A1[3] + b1r));
        stc8(rec + 8,  packF2(A2[0] + b2r, A2[1] + b2r));
        stc8(rec + 10, packF2(A2[2] + b2r, A2[3] + b2r));
      }
      sigc(bar, S4G, i, t + 1);
    }
  }

  // ======== epilogue: predsT (t,n,m) -> out (n,m,t) ========
  waitc(bar, S4, TSTEPS, 8);
  {
    float* trS = (float*)smem;
    for (int g = b; g < 504; g += 256) {
      int p0 = g * 16;
      for (int t0 = 0; t0 < 448; t0 += 16) {
        int tc = tid >> 4, pp = tid & 15;
        trS[tc * 17 + pp] = p.predsT[(size_t)(t0 + tc) * 8064 + p0 + pp];
        __syncthreads();
        p.out[(size_t)(p0 + (tid >> 4)) * 448 + t0 + (tid & 15)] = trS[(tid & 15) * 17 + (tid >> 4)];
        __syncthreads();
      }
    }
  }
}

// ---------------- host ----------------

extern "C" void kernel_launch(void* const* d_in, const int* in_sizes, int n_in,
                              void* d_out, int out_size, void* d_ws, size_t ws_size,
                              hipStream_t stream) {
  Ptrs p;
  p.aud = (const float*)d_in[0];
  p.mo  = (const float*)d_in[1];
  p.lxm = (const float*)d_in[2];
  p.vid = (const int*)d_in[3];
  p.eps = (const float*)d_in[4];
  p.csi_w0 = (const float*)d_in[5];  p.csi_b0 = (const float*)d_in[6];
  p.csi_w1 = (const float*)d_in[7];  p.csi_b1 = (const float*)d_in[8];
  p.csi_w2 = (const float*)d_in[9];  p.csi_b2 = (const float*)d_in[10];
  p.spk  = (const float*)d_in[11];
  p.mu_w = (const float*)d_in[12];   p.mu_b = (const float*)d_in[13];
  p.lv_w = (const float*)d_in[14];   p.lv_b = (const float*)d_in[15];
  p.embW = (const float*)d_in[16];   p.embB = (const float*)d_in[17];
  p.wih0 = (const float*)d_in[18];   p.whh0 = (const float*)d_in[19];
  p.bih0 = (const float*)d_in[20];   p.bhh0 = (const float*)d_in[21];
  p.wih1 = (const float*)d_in[22];   p.whh1 = (const float*)d_in[23];
  p.bih1 = (const float*)d_in[24];   p.bhh1 = (const float*)d_in[25];
  p.ln_g = (const float*)d_in[26];   p.ln_b = (const float*)d_in[27];
  p.predW = (const float*)d_in[28];  p.predB = (const float*)d_in[29];
  p.out = (float*)d_out;

  char* ws = (char*)d_ws;
  size_t off = 0;
  auto al = [&](size_t bytes) -> void* {
    void* r = (void*)(ws + off);
    off += (bytes + 255) & ~(size_t)255;
    return r;
  };
  p.bar    = (unsigned*)al(65536);
  p.mu5    = (float*)al(640);
  p.lv5    = (float*)al(640);
  p.gsbs   = (float*)al(1024);
  p.h0F    = (float*)al(262144);
  p.h1F    = (float*)al(262144);
  p.h0B    = (f16*)al(131072);
  p.h1B    = (f16*)al(131072);
  p.ineB   = (f16*)al(131072);
  p.ghP0   = (float*)al(1048576);
  p.ghP1   = (float*)al(1048576);
  p.x0     = (float*)al(262144);
  p.x1     = (float*)al(262144);
  p.predsT = (float*)al(14450688);
  p.xcat   = (f16*)al(22020096);
  p.whh0P  = (f16*)al(6291456);
  p.whh1P  = (f16*)al(6291456);
  p.wih0aP = (f16*)al(6291456);
  p.wih0bP = (f16*)al(2359296);
  p.wih1P  = (f16*)al(6291456);
  p.embWP  = (f16*)al(786432);
  p.predWP = (f16*)al(262144);

  k_init<<<64, 256, 0, stream>>>(p);

  k_pack<<<dim3(192, 32), 256, 0, stream>>>(p.whh0, p.whh0P, 1024, 0, 3072, 3072, nullptr);
  k_pack<<<dim3(192, 32), 256, 0, stream>>>(p.whh1, p.whh1P, 1024, 0, 3072, 3072, nullptr);
  k_pack<<<dim3(192, 32), 256, 0, stream>>>(p.wih0, p.wih0aP, 1024, 0, 3072, 3072, nullptr);
  k_pack<<<dim3(192, 12), 256, 0, stream>>>(p.wih0, p.wih0bP, 382, 1024, 3072, 3072, nullptr);
  k_pack<<<dim3(192, 32), 256, 0, stream>>>(p.wih1, p.wih1P, 1024, 0, 3072, 3072, nullptr);
  k_pack<<<dim3(64, 12), 256, 0, stream>>>(p.embW, p.embWP, 382, 0, 1024, 1024, nullptr);
  // predW packed with ln_g folded in (factored LayerNorm)
  k_pack<<<dim3(8, 32), 256, 0, stream>>>(p.predW, p.predWP, 1024, 0, 126, 126, p.ln_g);

  k_gsbs<<<1, 128, 0, stream>>>(p);
  k_csi1<<<256, 256, 0, stream>>>(p);
  k_csi2<<<256, 256, 0, stream>>>(p);
  k_csi3<<<512, 256, 0, stream>>>(p);
  k_gh<<<1536, 256, 0, stream>>>(p);
  k_style1<<<1, 256, 0, stream>>>(p);
  k_style2<<<3584, 256, 0, stream>>>(p);
  k_aud<<<1792, 256, 0, stream>>>(p);
  k_lxm<<<10752, 256, 0, stream>>>(p);
  k_premo0<<<32, 256, 0, stream>>>(p);
  k_padz<<<224, 256, 0, stream>>>(p);

  k_scan<<<256, 256, LDS_BYTES, stream>>>(p);

  (void)in_sizes; (void)n_in; (void)out_size; (void)ws_size;
}